// Round 1
// 2404.154 us; speedup vs baseline: 1.0185x; 1.0185x over previous
//
#include <hip/hip_runtime.h>
#include <math.h>

// Problem constants
#define NTOT   8192
#define BGR    128
#define NPER   64
#define EDIR   65536
#define EKEEP  32768
#define EPSC   1e-5f

typedef unsigned short ushortT;
typedef __attribute__((ext_vector_type(8))) short bf16x8;
typedef __attribute__((ext_vector_type(4))) float f32x4;

// Operand dtype codes: 0 = bf16, 1 = f32, 2 = runtime (read *flagp)
#define C_BF 0
#define C_F32 1
#define C_RT 2

// ---------------- dtype helpers ----------------
__device__ __forceinline__ float bf2f(ushortT u) {
    union { unsigned int i; float f; } v; v.i = ((unsigned int)u) << 16; return v.f;
}
__device__ __forceinline__ ushortT f2bf(float f) {
    unsigned int u = __float_as_uint(f);
    u += 0x7FFFu + ((u >> 16) & 1u);   // round to nearest even
    return (ushortT)(u >> 16);
}
__device__ __forceinline__ float get1(const void* p, long i, int f) {
    return f ? ((const float*)p)[i] : bf2f(((const ushortT*)p)[i]);
}
__device__ __forceinline__ float4 get4(const void* p, long i, int f) {
    if (f) return *(const float4*)((const float*)p + i);
    ushort4 u = *(const ushort4*)((const ushortT*)p + i);
    return make_float4(bf2f(u.x), bf2f(u.y), bf2f(u.z), bf2f(u.w));
}
__device__ __forceinline__ float ld1c(const float* p)   { return *p; }
__device__ __forceinline__ float ld1c(const ushortT* p) { return bf2f(*p); }
__device__ __forceinline__ void st1c(float* p, float v)   { *p = v; }
__device__ __forceinline__ void st1c(ushortT* p, float v) { *p = f2bf(v); }
__device__ __forceinline__ int clampi(int v, int lo, int hi) {
    return v < lo ? lo : (v > hi ? hi : v);
}

// direct global->LDS DMA, 16B per lane (lane-linear LDS destination required)
__device__ __forceinline__ void gld16(const void* g, void* l) {
    __builtin_amdgcn_global_load_lds(
        (const __attribute__((address_space(1))) unsigned int*)g,
        (__attribute__((address_space(3))) unsigned int*)l, 16, 0, 0);
}

// ---------------------------------------------------------------------------
// Float-input dtype detector (validated R7-R9).
// ---------------------------------------------------------------------------
__launch_bounds__(256)
__global__ void detect_k(const unsigned int* __restrict__ xw, int* __restrict__ flag)
{
    __shared__ int red[256];
    const int t = threadIdx.x;
    int hits = 0;
#pragma unroll
    for (int i = 0; i < 4; ++i) {
        const unsigned w = xw[t*4 + i];
        const unsigned eb = (w >> 7) & 0xFF;
        hits += (eb >= 100 && eb <= 150) ? 1 : 0;
    }
    red[t] = hits; __syncthreads();
#pragma unroll
    for (int s = 128; s > 0; s >>= 1) { if (t < s) red[t] += red[t+s]; __syncthreads(); }
    if (t == 0) *flag = (red[0] < 512) ? 1 : 0;
}

// ---------------------------------------------------------------------------
// Fast bf16 GEMM: C = alpha*(A @ B^T) (+bias f32) (+C). Both A and B read
// k-contiguous (B stored [n][k]). 128x128 tile/block, 4 waves (2x2), each
// wave 64x64 via 4x4 16x16x32 bf16 MFMA tiles, BK=32, fp32 accumulate.
// m97 structure: global_load_lds width=16 staging into linear [128][32] LDS
// (lane-order destination = t*16 bytes per wave issue), 2 barriers / K-step.
// Requires M%128==0 (per batch), N%128==0, K%32==0, lda/ldb%8==0.
// ---------------------------------------------------------------------------
template<class TC, bool BIAS, bool RESID>
__launch_bounds__(256)
__global__ void bgemm_k(const ushortT* __restrict__ A, const ushortT* __restrict__ B,
                        const float* __restrict__ bias, TC* __restrict__ C,
                        int K, int lda, int ldb, int ldc,
                        long sA, long sB, long sC, long biasOff, long bzStride,
                        float alpha)
{
    const int t = threadIdx.x;
    const int lane = t & 63, wave = t >> 6;
    const int l15 = lane & 15, quad = lane >> 4;
    const int wr = (wave >> 1) * 64, wc = (wave & 1) * 64;
    const int m0 = blockIdx.y * 128, n0 = blockIdx.x * 128;
    const long z = blockIdx.z;

    __shared__ __align__(16) ushortT As[128][32];   // linear: no pad (gload_lds)
    __shared__ __align__(16) ushortT Bs[128][32];

    f32x4 acc[4][4] = {};

    const int sr = t >> 2, sk = (t & 3) * 8;   // staging: 64 rows/issue, 16B/thread
    const ushortT* pA0 = A + z*sA + (long)(m0 + sr) * lda + sk;
    const ushortT* pA1 = pA0 + 64L * lda;
    const ushortT* pB0 = B + z*sB + (long)(n0 + sr) * ldb + sk;
    const ushortT* pB1 = pB0 + 64L * ldb;
    ushortT* lA0 = &As[sr][sk];
    ushortT* lA1 = &As[64 + sr][sk];
    ushortT* lB0 = &Bs[sr][sk];
    ushortT* lB1 = &Bs[64 + sr][sk];

    for (int k0 = 0; k0 < K; k0 += 32) {
        gld16(pA0 + k0, lA0);
        gld16(pA1 + k0, lA1);
        gld16(pB0 + k0, lB0);
        gld16(pB1 + k0, lB1);
        __syncthreads();   // compiler emits vmcnt(0) drain before s_barrier
        bf16x8 af[4], bfr[4];
#pragma unroll
        for (int i = 0; i < 4; ++i) {
            af[i]  = *(const bf16x8*)&As[wr + i*16 + l15][quad*8];
            bfr[i] = *(const bf16x8*)&Bs[wc + i*16 + l15][quad*8];
        }
#pragma unroll
        for (int mt = 0; mt < 4; ++mt)
#pragma unroll
            for (int nt = 0; nt < 4; ++nt)
                acc[mt][nt] = __builtin_amdgcn_mfma_f32_16x16x32_bf16(af[mt], bfr[nt], acc[mt][nt], 0, 0, 0);
        __syncthreads();
    }

    TC* Cb = C + z * sC;
#pragma unroll
    for (int nt = 0; nt < 4; ++nt) {
        const int col = n0 + wc + nt*16 + l15;
        const float bv = BIAS ? bias[biasOff + z*bzStride + col] : 0.f;
#pragma unroll
        for (int mt = 0; mt < 4; ++mt) {
#pragma unroll
            for (int r = 0; r < 4; ++r) {
                const int row = m0 + wr + mt*16 + quad*4 + r;
                TC* cp = Cb + (long)row * ldc + col;
                float val = alpha * acc[mt][nt][r] + bv;
                if constexpr (RESID) val += ld1c(cp);
                st1c(cp, val);
            }
        }
    }
}

// ---------------------------------------------------------------------------
// Generic MFMA GEMM (validated R8/R9; + CT transposed-store flag):
// C = alpha*(A @ B[^T]) (+bias[biasOff + z*bzStride + col]) (+C) (relu?)
// 64x64 tile/block, 4 waves, 16x16x32 bf16 MFMA, fp32 accumulate.
// ---------------------------------------------------------------------------
template<class TC, bool BT, bool BIAS, bool RELU, bool RESID, bool CT>
__launch_bounds__(256)
__global__ void gemm_k(const void* __restrict__ A, int cA, long aeOff,
                       const void* __restrict__ B, int cB, long beOff,
                       const void* __restrict__ bias, int cBias, long biasOff, long bzStride,
                       TC* __restrict__ C, const int* __restrict__ flagp,
                       int K, int lda, int ldb, int ldc,
                       long sA, long sB, long sC, float alpha)
{
    const int rtf = *flagp;
    const int fA = (cA == C_RT) ? rtf : cA;
    const int fB = (cB == C_RT) ? rtf : cB;

    const int t = threadIdx.x;
    const int lane = t & 63, wave = t >> 6;
    const int l15 = lane & 15, quad = lane >> 4;
    const int m0 = blockIdx.y * 64, n0 = blockIdx.x * 64;
    const long z = blockIdx.z;
    const long aOff = aeOff + z * sA, bOff = beOff + z * sB, cOff = z * sC;

    __shared__ __align__(16) ushortT As[64][40];
    __shared__ __align__(16) ushortT Bs[64][40];

    f32x4 acc[4] = {};

    const int ar = t >> 2, ak = (t & 3) * 8;
    const int bk = t & 31, bn = (t >> 5) * 8;

    for (int k0 = 0; k0 < K; k0 += 32) {
        {
            const long base = aOff + (long)(m0 + ar) * lda + (k0 + ak);
            float4 v0 = get4(A, base, fA);
            float4 v1 = get4(A, base + 4, fA);
            ushortT* dst = &As[ar][ak];
            dst[0]=f2bf(v0.x); dst[1]=f2bf(v0.y); dst[2]=f2bf(v0.z); dst[3]=f2bf(v0.w);
            dst[4]=f2bf(v1.x); dst[5]=f2bf(v1.y); dst[6]=f2bf(v1.z); dst[7]=f2bf(v1.w);
        }
        if constexpr (BT) {
            const long base = bOff + (long)(n0 + ar) * ldb + (k0 + ak);
            float4 v0 = get4(B, base, fB);
            float4 v1 = get4(B, base + 4, fB);
            ushortT* dst = &Bs[ar][ak];
            dst[0]=f2bf(v0.x); dst[1]=f2bf(v0.y); dst[2]=f2bf(v0.z); dst[3]=f2bf(v0.w);
            dst[4]=f2bf(v1.x); dst[5]=f2bf(v1.y); dst[6]=f2bf(v1.z); dst[7]=f2bf(v1.w);
        } else {
            const long base = bOff + (long)(k0 + bk) * ldb + (n0 + bn);
            float4 v0 = get4(B, base, fB);
            float4 v1 = get4(B, base + 4, fB);
            Bs[bn+0][bk] = f2bf(v0.x);
            Bs[bn+1][bk] = f2bf(v0.y);
            Bs[bn+2][bk] = f2bf(v0.z);
            Bs[bn+3][bk] = f2bf(v0.w);
            Bs[bn+4][bk] = f2bf(v1.x);
            Bs[bn+5][bk] = f2bf(v1.y);
            Bs[bn+6][bk] = f2bf(v1.z);
            Bs[bn+7][bk] = f2bf(v1.w);
        }
        __syncthreads();
        const bf16x8 af = *(const bf16x8*)&As[wave*16 + l15][quad*8];
#pragma unroll
        for (int nt = 0; nt < 4; ++nt) {
            const bf16x8 bf = *(const bf16x8*)&Bs[nt*16 + l15][quad*8];
            acc[nt] = __builtin_amdgcn_mfma_f32_16x16x32_bf16(af, bf, acc[nt], 0, 0, 0);
        }
        __syncthreads();
    }

    const int fBias = BIAS ? ((cBias == C_RT) ? rtf : cBias) : 0;
#pragma unroll
    for (int nt = 0; nt < 4; ++nt) {
        const int col = n0 + nt*16 + l15;
        const float bv = BIAS ? get1(bias, biasOff + z*bzStride + col, fBias) : 0.f;
#pragma unroll
        for (int r = 0; r < 4; ++r) {
            const int row = m0 + wave*16 + quad*4 + r;
            TC* cp = CT ? (C + cOff + (long)col * ldc + row)
                        : (C + cOff + (long)row * ldc + col);
            float val = alpha * acc[nt][r] + bv;
            if constexpr (RESID) val += ld1c(cp);
            if constexpr (RELU)  val = fmaxf(val, 0.f);
            st1c(cp, val);
        }
    }
}

// ---------------- block reduction (256 threads) ----------------
__device__ __forceinline__ float blockReduceSum(float v, float* red, int t)
{
    red[t] = v; __syncthreads();
#pragma unroll
    for (int s = 128; s > 0; s >>= 1) {
        if (t < s) red[t] += red[t + s];
        __syncthreads();
    }
    const float r = red[0];
    __syncthreads();
    return r;
}

// ---------------------------------------------------------------------------
// colcomb: out[d] = sum_c v[voff+c] * W[c*1536+d] + b[d]   (f32 out), grid 6x256
// ---------------------------------------------------------------------------
__launch_bounds__(256)
__global__ void colcomb_k(const void* __restrict__ v, int cv, long voff,
                          const void* __restrict__ W, int cW,
                          const void* __restrict__ b, int cb,
                          float* __restrict__ out, const int* __restrict__ flagp)
{
    const int rtf = *flagp;
    const int fv = (cv == C_RT) ? rtf : cv;
    const int fW = (cW == C_RT) ? rtf : cW;
    const int fb = (cb == C_RT) ? rtf : cb;
    const int d = blockIdx.x*256 + threadIdx.x;
    float a0 = 0.f, a1 = 0.f;
    for (int c = 0; c < 1536; c += 2) {
        a0 += get1(v, voff+c+0, fv) * get1(W, (long)(c+0)*1536 + d, fW);
        a1 += get1(v, voff+c+1, fv) * get1(W, (long)(c+1)*1536 + d, fW);
    }
    out[d] = a0 + a1 + get1(b, d, fb);
}

// ---------------------------------------------------------------------------
// rowdot: out[r] = scale * sum_c bf2f(W[r*1536+c]) * v[c]   grid 1536 x 256
// ---------------------------------------------------------------------------
__launch_bounds__(256)
__global__ void rowdot_k(const ushortT* __restrict__ W, const float* __restrict__ v,
                         float* __restrict__ out, float scale)
{
    const int r = blockIdx.x, t = threadIdx.x;
    __shared__ float red[256];
    float p = 0.f;
    for (int c = t; c < 1536; c += 256) p += bf2f(W[(long)r*1536 + c]) * v[c];
    const float tot = blockReduceSum(p, red, t);
    if (t == 0) out[r] = scale * tot;
}

// ---------------------------------------------------------------------------
// gconv1 fused (unchanged — validated)
// ---------------------------------------------------------------------------
__launch_bounds__(256)
__global__ void gconv1_k(int b0, const void* __restrict__ x, const int* __restrict__ edges,
                         const void* __restrict__ ea,
                         const void* __restrict__ wembW, const void* __restrict__ wembB,
                         const void* __restrict__ Wrel, const void* __restrict__ brel,
                         const void* __restrict__ Wroot, ushortT* __restrict__ h1,
                         const int* __restrict__ flagp)
{
    const int f = *flagp;
    const int bl = blockIdx.x, g = b0 + bl, t = threadIdx.x;
    __shared__ float s_x[64][5];
    __shared__ float s_agg[64][5];
    __shared__ int   s_cnt[64];
    __shared__ int   s_off[65];
    __shared__ int   s_src[512];
    __shared__ float s_w[512];

    if (t < 64) s_cnt[t] = 0;
    if (t < 320) s_x[t/5][t%5] = get1(x, (long)(g*64 + t/5)*5 + (t%5), f);
    __syncthreads();

    const float w0 = get1(wembW,0,f), w1 = get1(wembW,1,f), w2 = get1(wembW,2,f);
    const float wb = get1(wembB,0,f);
    int sl[2], dl[2], slot[2]; float wv[2];
#pragma unroll
    for (int e2 = 0; e2 < 2; ++e2) {
        const int e = g*512 + t + 256*e2;
        const int s = edges[e], d = edges[EDIR + e];
        sl[e2] = clampi(s - g*64, 0, 63); dl[e2] = clampi(d - g*64, 0, 63);
        const float a0 = get1(ea, 2L*e, f), a1 = get1(ea, 2L*e+1, f);
        wv[e2] = fmaxf(a0*w0 + ((a1 < 0.5f) ? w1 : w2) + wb, 0.f);
        slot[e2] = atomicAdd(&s_cnt[dl[e2]], 1);
    }
    __syncthreads();
    if (t == 0) {
        int r = 0;
        for (int i = 0; i < 64; ++i) { s_off[i] = r; r += s_cnt[i]; }
        s_off[64] = r;
    }
    __syncthreads();
#pragma unroll
    for (int e2 = 0; e2 < 2; ++e2) {
        const int p = s_off[dl[e2]] + slot[e2];
        s_src[p] = sl[e2]; s_w[p] = wv[e2];
    }
    __syncthreads();
    if (t < 320) {
        const int n = t/5, k = t%5;
        float acc = 0.f;
        for (int i = s_off[n]; i < s_off[n+1]; ++i) acc += s_w[i] * s_x[s_src[i]][k];
        s_agg[n][k] = acc;
    }
    __syncthreads();
    float wr[5], wo[5];
#pragma unroll
    for (int k = 0; k < 5; ++k) { wr[k] = get1(Wrel, k*256 + t, f); wo[k] = get1(Wroot, k*256 + t, f); }
    const float bb = get1(brel, t, f);
    for (int n = 0; n < 64; ++n) {
        float v = bb;
#pragma unroll
        for (int k = 0; k < 5; ++k) v += s_agg[n][k]*wr[k] + s_x[n][k]*wo[k];
        h1[(bl*64 + n)*256 + t] = f2bf(fmaxf(v, 0.f));
    }
}

// ---------------------------------------------------------------------------
// gconv2 aggregation (unchanged — validated)
// ---------------------------------------------------------------------------
__launch_bounds__(256)
__global__ void gconv2_agg_k(int b0, const ushortT* __restrict__ h1, const int* __restrict__ edges,
                             const void* __restrict__ ea,
                             const void* __restrict__ wembW, const void* __restrict__ wembB,
                             ushortT* __restrict__ agg2, const int* __restrict__ flagp)
{
    const int f = *flagp;
    const int bl = blockIdx.x, g = b0 + bl, t = threadIdx.x;
    __shared__ int   s_cnt[64];
    __shared__ int   s_off[65];
    __shared__ int   s_src[512];
    __shared__ float s_w[512];

    if (t < 64) s_cnt[t] = 0;
    __syncthreads();

    const float w0 = get1(wembW,0,f), w1 = get1(wembW,1,f), w2 = get1(wembW,2,f);
    const float wb = get1(wembB,0,f);
    int sl[2], dl[2], slot[2]; float wv[2];
#pragma unroll
    for (int e2 = 0; e2 < 2; ++e2) {
        const int e = g*512 + t + 256*e2;
        const int s = edges[e], d = edges[EDIR + e];
        sl[e2] = clampi(s - g*64, 0, 63); dl[e2] = clampi(d - g*64, 0, 63);
        const float a0 = get1(ea, 2L*e, f), a1 = get1(ea, 2L*e+1, f);
        wv[e2] = fmaxf(a0*w0 + ((a1 < 0.5f) ? w1 : w2) + wb, 0.f);
        slot[e2] = atomicAdd(&s_cnt[dl[e2]], 1);
    }
    __syncthreads();
    if (t == 0) {
        int r = 0;
        for (int i = 0; i < 64; ++i) { s_off[i] = r; r += s_cnt[i]; }
        s_off[64] = r;
    }
    __syncthreads();
#pragma unroll
    for (int e2 = 0; e2 < 2; ++e2) {
        const int p = s_off[dl[e2]] + slot[e2];
        s_src[p] = sl[e2]; s_w[p] = wv[e2];
    }
    __syncthreads();
    for (int n = 0; n < 64; ++n) {
        float acc = 0.f;
        const int i0 = s_off[n], i1 = s_off[n+1];
        for (int i = i0; i < i1; ++i)
            acc += s_w[i] * bf2f(h1[(bl*64 + s_src[i])*256 + t]);
        agg2[(bl*64 + n)*256 + t] = f2bf(acc);
    }
}

// ---------------------------------------------------------------------------
// GraphNorm (unchanged — validated)
// ---------------------------------------------------------------------------
__launch_bounds__(256)
__global__ void gnorm_k(ushortT* __restrict__ h, const void* __restrict__ gw,
                        const void* __restrict__ gb, const void* __restrict__ gms,
                        const int* __restrict__ flagp)
{
    const int f0 = *flagp;
    const int bl = blockIdx.x, t = threadIdx.x;
#pragma unroll
    for (int f2 = 0; f2 < 2; ++f2) {
        const int f = t + 256*f2;
        float acc = 0.f;
        for (int n = 0; n < 64; ++n) acc += bf2f(h[(bl*64+n)*512 + f]);
        const float m2 = get1(gms, f, f0) * (acc * (1.f/64.f));
        float v = 0.f;
        for (int n = 0; n < 64; ++n) { const float d = bf2f(h[(bl*64+n)*512 + f]) - m2; v += d*d; }
        const float rs = rsqrtf(v*(1.f/64.f) + EPSC);
        const float g = get1(gw, f, f0), bb = get1(gb, f, f0);
        for (int n = 0; n < 64; ++n) {
            const int idx = (bl*64+n)*512 + f;
            h[idx] = f2bf(g * (bf2f(h[idx]) - m2) * rs + bb);
        }
    }
}

// ---------------------------------------------------------------------------
// SplitSyndromes sort (unchanged — validated)
// ---------------------------------------------------------------------------
__launch_bounds__(256)
__global__ void sort_k(const int* __restrict__ edges, int* __restrict__ sorted_orig,
                       int* __restrict__ se, int* __restrict__ te)
{
    const int b = blockIdx.x, t = threadIdx.x;
    __shared__ int s_keep[512];
    __shared__ int s_key[512];
    __shared__ int s_ckey[256];
    __shared__ int s_corig[256];
#pragma unroll
    for (int e2 = 0; e2 < 2; ++e2) {
        const int el = t + 256*e2;
        const int e = b*512 + el;
        const int s = edges[e], d = edges[EDIR + e];
        s_keep[el] = (s > d) ? 1 : 0;
        s_key[el]  = ((s - b*64) << 6) | (d - b*64);
    }
    __syncthreads();
#pragma unroll
    for (int e2 = 0; e2 < 2; ++e2) {
        const int el = t + 256*e2;
        if (s_keep[el]) {
            int pos = 0;
            for (int j = 0; j < el; ++j) pos += s_keep[j];
            s_ckey[pos]  = s_key[el];
            s_corig[pos] = b*512 + el;
        }
    }
    __syncthreads();
    const int ki = s_ckey[t];
    int rank = 0;
    for (int j = 0; j < 256; ++j) {
        const int kj = s_ckey[j];
        rank += (kj < ki || (kj == ki && j < t)) ? 1 : 0;
    }
    const int orig = s_corig[t];
    const int p = b*256 + rank;
    sorted_orig[p] = orig;
    se[p] = edges[orig];
    te[p] = edges[EDIR + orig];
}

// ---------------------------------------------------------------------------
// Build F_c + bvec[ge] = F[e] . kb  (unchanged — validated)
// ---------------------------------------------------------------------------
__launch_bounds__(256)
__global__ void fbuild_k(int b0, int maxn, const ushortT* __restrict__ h,
                         const int* __restrict__ sorted_orig,
                         const int* __restrict__ se, const int* __restrict__ te,
                         const void* __restrict__ ea,
                         const void* __restrict__ eW, const void* __restrict__ eB,
                         const float* __restrict__ kb,
                         ushortT* __restrict__ F, float* __restrict__ bvec,
                         const int* __restrict__ flagp)
{
    const int fl = *flagp;
    const int e = blockIdx.x, t = threadIdx.x;
    __shared__ float red[256];
    const int ge = b0*256 + e;
    const int s = clampi(se[ge] - b0*64, 0, maxn);
    const int d = clampi(te[ge] - b0*64, 0, maxn);
    const int orig = clampi(sorted_orig[ge], 0, EDIR-1);
    const float a0 = get1(ea, 2L*orig, fl), a1 = get1(ea, 2L*orig + 1, fl);
    float partial = 0.f;
#pragma unroll
    for (int c = 0; c < 6; ++c) {
        const int col = c*256 + t;
        float v;
        if (c < 2) {
            v = bf2f(h[(long)s*512 + col]);
        } else if (c < 4) {
            const int ff = col - 512;
            v = fmaxf(a0*get1(eW, ff, fl)
                      + ((a1 < 0.5f) ? get1(eW, 512+ff, fl) : get1(eW, 1024+ff, fl))
                      + get1(eB, ff, fl), 0.f);
        } else {
            v = bf2f(h[(long)d*512 + (col - 1024)]);
        }
        F[(long)e*1536 + col] = f2bf(v);
        partial += v * kb[col];
    }
    const float tot = blockReduceSum(partial, red, t);
    if (t == 0) bvec[ge] = tot;
}

// ---------------- row softmax (unchanged — validated) ----------------
__launch_bounds__(256)
__global__ void softmax_k(float* __restrict__ S)
{
    const long row = blockIdx.x;
    const int t = threadIdx.x;
    __shared__ float red[256];
    const float v = S[row*256 + t];
    red[t] = v; __syncthreads();
#pragma unroll
    for (int s = 128; s > 0; s >>= 1) { if (t < s) red[t] = fmaxf(red[t], red[t+s]); __syncthreads(); }
    const float mx = red[0]; __syncthreads();
    const float e = __expf(v - mx);
    red[t] = e; __syncthreads();
#pragma unroll
    for (int s = 128; s > 0; s >>= 1) { if (t < s) red[t] += red[t+s]; __syncthreads(); }
    const float sum = red[0];
    S[row*256 + t] = e / sum;
}

// ---------------- fused LayerNorm + head dot (unchanged — validated) --------
__launch_bounds__(256)
__global__ void ln_head_k(int b0, const ushortT* __restrict__ F, const void* __restrict__ lng,
                          const void* __restrict__ lnb, const void* __restrict__ hW,
                          const void* __restrict__ hB, float* __restrict__ gout,
                          const int* __restrict__ flagp)
{
    const int fl = *flagp;
    const int e = blockIdx.x, t = threadIdx.x;
    __shared__ float red[256];
    float xv[6];
    float s = 0.f;
#pragma unroll
    for (int c = 0; c < 6; ++c) { xv[c] = bf2f(F[(long)e*1536 + c*256 + t]); s += xv[c]; }
    const float tot = blockReduceSum(s, red, t);
    const float mu = tot * (1.f/1536.f);
    float ss = 0.f;
#pragma unroll
    for (int c = 0; c < 6; ++c) { const float d = xv[c] - mu; ss += d*d; }
    const float tot2 = blockReduceSum(ss, red, t);
    const float rs = rsqrtf(tot2 * (1.f/1536.f) + EPSC);
    float p = 0.f;
#pragma unroll
    for (int c = 0; c < 6; ++c) {
        const int col = c*256 + t;
        p += (get1(lng, col, fl) * (xv[c] - mu) * rs + get1(lnb, col, fl)) * get1(hW, col, fl);
    }
    const float tot3 = blockReduceSum(p, red, t);
    if (t == 0) gout[b0*256 + e] = tot3 + get1(hB, 0, fl);
}

// ---------------- final output assembly (unchanged — validated) -------------
__launch_bounds__(128)
__global__ void final_k(const float* __restrict__ gout, const int* __restrict__ se,
                        const int* __restrict__ te, const int* __restrict__ sorted_orig,
                        const void* __restrict__ ea, float* __restrict__ out,
                        const int* __restrict__ flagp)
{
    const int fl = *flagp;
    const int b = blockIdx.x, j = threadIdx.x;
    const int e0 = b*256 + 2*j, e1 = e0 + 1;
    const float p0 = gout[e0], p1 = gout[e1];
    const int idx = (p1 < p0) ? 1 : 0;
    const float val = idx ? p1 : p0;
    const int eo = idx ? e1 : e0;
    const int orig = clampi(sorted_orig[eo], 0, EDIR-1);
    const float cls = get1(ea, 2L*orig + 1, fl);
    out[(b*128 + j)*2 + 0] = (float)se[e0];
    out[(b*128 + j)*2 + 1] = (float)te[e0];
    out[32768 + b*128 + j] = val;
    out[32768 + 16384 + b*128 + j] = cls;
}

// ---------------------------------------------------------------------------
// Launch: phase-W precombination emits MpT/WvoT (transposed, bf16) so the hot
// GEMMs run on the fast k-contiguous bf16 path.
// ---------------------------------------------------------------------------
extern "C" void kernel_launch(void* const* d_in, const int* in_sizes, int n_in,
                              void* d_out, int out_size, void* d_ws, size_t ws_size,
                              hipStream_t stream)
{
    (void)out_size;

    const void* x     = d_in[0];
    const int*  edges = (const int*)d_in[1];
    const void* ea    = d_in[2];

    int ws0 = 3;
    while (ws0 < n_in && in_sizes[ws0] != 3) ++ws0;
    if (ws0 + 27 > n_in) ws0 = 5;

    const void* wembW  = d_in[ws0 + 0];
    const void* wembB  = d_in[ws0 + 1];
    const void* g1Wrel = d_in[ws0 + 2];
    const void* g1brel = d_in[ws0 + 3];
    const void* g1Wroot= d_in[ws0 + 4];
    const void* g2Wrel = d_in[ws0 + 5];
    const void* g2brel = d_in[ws0 + 6];
    const void* g2Wroot= d_in[ws0 + 7];
    const void* gnw    = d_in[ws0 + 8];
    const void* gnb    = d_in[ws0 + 9];
    const void* gnms   = d_in[ws0 + 10];
    const void* eembW  = d_in[ws0 + 11];
    const void* eembB  = d_in[ws0 + 12];
    const void* qkvW   = d_in[ws0 + 13];
    const void* qkvb   = d_in[ws0 + 14];
    const void* inWq   = d_in[ws0 + 15];
    const void* inWk   = d_in[ws0 + 16];
    const void* inWv   = d_in[ws0 + 17];
    const void* inbq   = d_in[ws0 + 18];
    // inbk (ws0+19): row-constant score terms -> drop in softmax
    const void* inbv   = d_in[ws0 + 20];
    const void* outW   = d_in[ws0 + 21];
    const void* outb   = d_in[ws0 + 22];
    const void* lng    = d_in[ws0 + 23];
    const void* lnb    = d_in[ws0 + 24];
    const void* headW  = d_in[ws0 + 25];
    const void* headb  = d_in[ws0 + 26];

    char* ws = (char*)d_ws;
    size_t off = 0;
    auto alloc = [&](size_t bytes) {
        void* p = ws + off;
        off = (off + bytes + 255) & ~(size_t)255;
        return p;
    };
    // ---- fixed region (~10.6 MB) ----
    int*     dflag  = (int*)    alloc(256);
    float*   gout   = (float*)  alloc(EKEEP*4);
    int*     sorted = (int*)    alloc(EKEEP*4);
    int*     seg    = (int*)    alloc(EKEEP*4);
    int*     teg    = (int*)    alloc(EKEEP*4);
    float*   bvec   = (float*)  alloc(EKEEP*4);
    float*   bqc    = (float*)  alloc(1536*4);
    float*   bvc    = (float*)  alloc(1536*4);
    float*   kb     = (float*)  alloc(1536*4);
    float*   bvo    = (float*)  alloc(1536*4);
    ushortT* MpT    = (ushortT*)alloc(1536L*1536*2);   // Mp^T, [n][k]
    ushortT* WvoT   = (ushortT*)alloc(1536L*1536*2);   // Wvo^T, [n][k]
    const size_t fixedB = off;

    // union region: phase-W (Wqc|Wkc, Wvc reuses Wqc) vs chunk scratch
    char* uni = ws + off;
    ushortT* Wqc = (ushortT*)uni;
    ushortT* Wkc = (ushortT*)(uni + ((1536L*1536*2 + 255) & ~255L));
    ushortT* Wvc = Wqc;

    const size_t perG = 64L*512*2 + 2L*64*256*2 + 2L*256*1536*2 + 256L*256*4; // 1.97MB
    int G = 128;
    while (G > 1 && fixedB + (size_t)G*perG + 8192 > ws_size) G >>= 1;

    size_t coff = fixedB;
    auto calloc2 = [&](size_t bytes) {
        void* p = ws + coff;
        coff = (coff + bytes + 255) & ~(size_t)255;
        return p;
    };
    ushortT* h_c  = (ushortT*)calloc2((size_t)G*64*512*2);
    ushortT* h1_c = (ushortT*)calloc2((size_t)G*64*256*2);
    ushortT* ag_c = (ushortT*)calloc2((size_t)G*64*256*2);
    ushortT* F_c  = (ushortT*)calloc2((size_t)G*256*1536*2);
    ushortT* T_c  = (ushortT*)calloc2((size_t)G*256*1536*2);
    float*   S_c  = (float*)  calloc2((size_t)G*256*256*4);

    const float scale = 0.02551551815399144f;  // 1/sqrt(1536)
    const dim3 blk(256);

    detect_k<<<1, blk, 0, stream>>>((const unsigned int*)x, dflag);
    sort_k<<<128, blk, 0, stream>>>(edges, sorted, seg, teg);

    // ---- phase W: weight precombination ----
    gemm_k<ushortT,false,false,false,false,false><<<dim3(24,24,1), blk, 0, stream>>>(
        qkvW, C_RT, 0, inWq, C_RT, 0, (const void*)nullptr, C_BF, 0, 0,
        Wqc, dflag, 1536, 4608, 1536, 1536, 0,0,0, 1.f);
    gemm_k<ushortT,false,false,false,false,false><<<dim3(24,24,1), blk, 0, stream>>>(
        qkvW, C_RT, 1536, inWk, C_RT, 0, (const void*)nullptr, C_BF, 0, 0,
        Wkc, dflag, 1536, 4608, 1536, 1536, 0,0,0, 1.f);
    colcomb_k<<<6, blk, 0, stream>>>(qkvb, C_RT, 0, inWq, C_RT, inbq, C_RT, bqc, dflag);
    // MpT = scale * Wkc @ Wqc^T   (Mp^T directly — operands swapped)
    gemm_k<ushortT,true,false,false,false,false><<<dim3(24,24,1), blk, 0, stream>>>(
        Wkc, C_BF, 0, Wqc, C_BF, 0, (const void*)nullptr, C_BF, 0, 0,
        MpT, dflag, 1536, 1536, 1536, 1536, 0,0,0, scale);
    // kb = scale * Wkc @ bqc
    rowdot_k<<<1536, blk, 0, stream>>>(Wkc, bqc, kb, scale);
    // Wvc = qkvW[:,3072:4608] @ inWv  (reuses Wqc slot)
    gemm_k<ushortT,false,false,false,false,false><<<dim3(24,24,1), blk, 0, stream>>>(
        qkvW, C_RT, 3072, inWv, C_RT, 0, (const void*)nullptr, C_BF, 0, 0,
        Wvc, dflag, 1536, 4608, 1536, 1536, 0,0,0, 1.f);
    colcomb_k<<<6, blk, 0, stream>>>(qkvb, C_RT, 3072, inWv, C_RT, inbv, C_RT, bvc, dflag);
    // WvoT = (Wvc @ outW)^T  via transposed store
    gemm_k<ushortT,false,false,false,false,true><<<dim3(24,24,1), blk, 0, stream>>>(
        Wvc, C_BF, 0, outW, C_RT, 0, (const void*)nullptr, C_BF, 0, 0,
        WvoT, dflag, 1536, 1536, 1536, 1536, 0,0,0, 1.f);
    colcomb_k<<<6, blk, 0, stream>>>(bvc, C_F32, 0, outW, C_RT, outb, C_RT, bvo, dflag);

    // ---- per-chunk pipeline ----
    const int nchunk = 128 / G;
    const int EC = G * 256;
    for (int c = 0; c < nchunk; ++c) {
        const int b0 = c * G;
        gconv1_k<<<G, blk, 0, stream>>>(b0, x, edges, ea, wembW, wembB,
                                        g1Wrel, g1brel, g1Wroot, h1_c, dflag);
        gconv2_agg_k<<<G, blk, 0, stream>>>(b0, h1_c, edges, ea, wembW, wembB, ag_c, dflag);
        gemm_k<ushortT,false,true,false,false,false><<<dim3(8,G,1), blk, 0, stream>>>(
            ag_c, C_BF, 0, g2Wrel, C_RT, 0, g2brel, C_RT, 0, 0, h_c, dflag,
            256, 256, 512, 512, 0,0,0, 1.f);
        gemm_k<ushortT,false,false,true,true,false><<<dim3(8,G,1), blk, 0, stream>>>(
            h1_c, C_BF, 0, g2Wroot, C_RT, 0, (const void*)nullptr, C_BF, 0, 0, h_c, dflag,
            256, 256, 512, 512, 0,0,0, 1.f);
        gnorm_k<<<G, blk, 0, stream>>>(h_c, gnw, gnb, gnms, dflag);
        fbuild_k<<<EC, blk, 0, stream>>>(b0, G*64-1, h_c, sorted, seg, teg, ea,
                                         eembW, eembB, kb, F_c, bvec, dflag);
        // T = F @ MpT^T   (fast bf16 path)
        bgemm_k<ushortT,false,false><<<dim3(12, EC/128, 1), blk, 0, stream>>>(
            F_c, MpT, nullptr, T_c, 1536, 1536, 1536, 1536, 0,0,0, 0,0, 1.f);
        // S_b = T_b @ F_b^T + bvec
        bgemm_k<float,true,false><<<dim3(2, 2, G), blk, 0, stream>>>(
            T_c, F_c, bvec + (long)b0*256, S_c, 1536, 1536, 1536, 256,
            256L*1536, 256L*1536, 65536L, 0, 256, 1.f);
        softmax_k<<<EC, blk, 0, stream>>>(S_c);
        // R_b = P_b @ F_b  -> T_c (generic path: A is f32)
        gemm_k<ushortT,false,false,false,false,false><<<dim3(24,4,G), blk, 0, stream>>>(
            S_c, C_F32, 0, F_c, C_BF, 0, (const void*)nullptr, C_BF, 0, 0, T_c, dflag,
            256, 256, 1536, 1536, 65536L, 256L*1536, 256L*1536, 1.f);
        // F += R @ WvoT^T + bvo   (fast bf16 path, residual)
        bgemm_k<ushortT,true,true><<<dim3(12, EC/128, 1), blk, 0, stream>>>(
            T_c, WvoT, bvo, F_c, 1536, 1536, 1536, 1536, 0,0,0, 0,0, 1.f);
        ln_head_k<<<EC, blk, 0, stream>>>(b0, F_c, lng, lnb, headW, headb, gout, dflag);
    }

    final_k<<<128, dim3(128), 0, stream>>>(gout, seg, teg, sorted, ea, (float*)d_out, dflag);
}

// Round 2
// 2277.033 us; speedup vs baseline: 1.0754x; 1.0558x over previous
//
#include <hip/hip_runtime.h>
#include <math.h>

// Problem constants
#define NTOT   8192
#define BGR    128
#define NPER   64
#define EDIR   65536
#define EKEEP  32768
#define EPSC   1e-5f

typedef unsigned short ushortT;
typedef __attribute__((ext_vector_type(8))) short bf16x8;
typedef __attribute__((ext_vector_type(4))) float f32x4;

// Operand dtype codes: 0 = bf16, 1 = f32, 2 = runtime (read *flagp)
#define C_BF 0
#define C_F32 1
#define C_RT 2

// ---------------- dtype helpers ----------------
__device__ __forceinline__ float bf2f(ushortT u) {
    union { unsigned int i; float f; } v; v.i = ((unsigned int)u) << 16; return v.f;
}
__device__ __forceinline__ ushortT f2bf(float f) {
    unsigned int u = __float_as_uint(f);
    u += 0x7FFFu + ((u >> 16) & 1u);   // round to nearest even
    return (ushortT)(u >> 16);
}
__device__ __forceinline__ float get1(const void* p, long i, int f) {
    return f ? ((const float*)p)[i] : bf2f(((const ushortT*)p)[i]);
}
__device__ __forceinline__ float4 get4(const void* p, long i, int f) {
    if (f) return *(const float4*)((const float*)p + i);
    ushort4 u = *(const ushort4*)((const ushortT*)p + i);
    return make_float4(bf2f(u.x), bf2f(u.y), bf2f(u.z), bf2f(u.w));
}
__device__ __forceinline__ float ld1c(const float* p)   { return *p; }
__device__ __forceinline__ float ld1c(const ushortT* p) { return bf2f(*p); }
__device__ __forceinline__ void st1c(float* p, float v)   { *p = v; }
__device__ __forceinline__ void st1c(ushortT* p, float v) { *p = f2bf(v); }
__device__ __forceinline__ int clampi(int v, int lo, int hi) {
    return v < lo ? lo : (v > hi ? hi : v);
}

// direct global->LDS DMA, 16B per lane (lane-linear LDS destination required)
__device__ __forceinline__ void gld16(const void* g, void* l) {
    __builtin_amdgcn_global_load_lds(
        (const __attribute__((address_space(1))) unsigned int*)g,
        (__attribute__((address_space(3))) unsigned int*)l, 16, 0, 0);
}

// Bijective XCD-chunked block-id swizzle (m204): hardware blocks round-robin
// XCDs by flat%8; remap so each XCD owns a CONTIGUOUS chunk of work ids ->
// blocks sharing operand panels co-reside in one XCD's L2.
__device__ __forceinline__ int xcd_swz(int flat, int nwg) {
    const int q = nwg >> 3, r = nwg & 7;
    const int xcd = flat & 7, idx = flat >> 3;
    return (xcd < r ? xcd * (q + 1) : r * (q + 1) + (xcd - r) * q) + idx;
}

// ---------------------------------------------------------------------------
// Float-input dtype detector (validated R7-R9).
// ---------------------------------------------------------------------------
__launch_bounds__(256)
__global__ void detect_k(const unsigned int* __restrict__ xw, int* __restrict__ flag)
{
    __shared__ int red[256];
    const int t = threadIdx.x;
    int hits = 0;
#pragma unroll
    for (int i = 0; i < 4; ++i) {
        const unsigned w = xw[t*4 + i];
        const unsigned eb = (w >> 7) & 0xFF;
        hits += (eb >= 100 && eb <= 150) ? 1 : 0;
    }
    red[t] = hits; __syncthreads();
#pragma unroll
    for (int s = 128; s > 0; s >>= 1) { if (t < s) red[t] += red[t+s]; __syncthreads(); }
    if (t == 0) *flag = (red[0] < 512) ? 1 : 0;
}

// ---------------------------------------------------------------------------
// Fast bf16 GEMM: C = alpha*(A @ B^T) (+bias f32) (+C). Both A and B read
// k-contiguous (B stored [n][k]). 128x128 tile/block, 4 waves (2x2), each
// wave 64x64 via 4x4 16x16x32 bf16 MFMA tiles, BK=32, fp32 accumulate.
// m97 structure: global_load_lds width=16 staging into linear [128][32] LDS,
// 2 barriers / K-step. XCD-chunked swizzle for per-XCD L2 operand locality.
// Requires M%128==0 (per batch), N%128==0, K%32==0, lda/ldb%8==0.
// ---------------------------------------------------------------------------
template<class TC, bool BIAS, bool RESID>
__launch_bounds__(256)
__global__ void bgemm_k(const ushortT* __restrict__ A, const ushortT* __restrict__ B,
                        const float* __restrict__ bias, TC* __restrict__ C,
                        int K, int lda, int ldb, int ldc,
                        long sA, long sB, long sC, long biasOff, long bzStride,
                        float alpha)
{
    const int t = threadIdx.x;
    const int lane = t & 63, wave = t >> 6;
    const int l15 = lane & 15, quad = lane >> 4;
    const int wr = (wave >> 1) * 64, wc = (wave & 1) * 64;

    // XCD-chunked remap of the flattened grid (bijective)
    const int gx = gridDim.x, gy = gridDim.y;
    const int nwg = gx * gy * (int)gridDim.z;
    const int flat = xcd_swz(blockIdx.x + gx * (blockIdx.y + gy * blockIdx.z), nwg);
    const int bx = flat % gx;
    const int by = (flat / gx) % gy;
    const int bz = flat / (gx * gy);

    const int m0 = by * 128, n0 = bx * 128;
    const long z = bz;

    __shared__ __align__(16) ushortT As[128][32];   // linear: no pad (gload_lds)
    __shared__ __align__(16) ushortT Bs[128][32];

    f32x4 acc[4][4] = {};

    const int sr = t >> 2, sk = (t & 3) * 8;   // staging: 64 rows/issue, 16B/thread
    const ushortT* pA0 = A + z*sA + (long)(m0 + sr) * lda + sk;
    const ushortT* pA1 = pA0 + 64L * lda;
    const ushortT* pB0 = B + z*sB + (long)(n0 + sr) * ldb + sk;
    const ushortT* pB1 = pB0 + 64L * ldb;
    ushortT* lA0 = &As[sr][sk];
    ushortT* lA1 = &As[64 + sr][sk];
    ushortT* lB0 = &Bs[sr][sk];
    ushortT* lB1 = &Bs[64 + sr][sk];

    for (int k0 = 0; k0 < K; k0 += 32) {
        gld16(pA0 + k0, lA0);
        gld16(pA1 + k0, lA1);
        gld16(pB0 + k0, lB0);
        gld16(pB1 + k0, lB1);
        __syncthreads();   // compiler emits vmcnt(0) drain before s_barrier
        bf16x8 af[4], bfr[4];
#pragma unroll
        for (int i = 0; i < 4; ++i) {
            af[i]  = *(const bf16x8*)&As[wr + i*16 + l15][quad*8];
            bfr[i] = *(const bf16x8*)&Bs[wc + i*16 + l15][quad*8];
        }
#pragma unroll
        for (int mt = 0; mt < 4; ++mt)
#pragma unroll
            for (int nt = 0; nt < 4; ++nt)
                acc[mt][nt] = __builtin_amdgcn_mfma_f32_16x16x32_bf16(af[mt], bfr[nt], acc[mt][nt], 0, 0, 0);
        __syncthreads();
    }

    TC* Cb = C + z * sC;
#pragma unroll
    for (int nt = 0; nt < 4; ++nt) {
        const int col = n0 + wc + nt*16 + l15;
        const float bv = BIAS ? bias[biasOff + z*bzStride + col] : 0.f;
#pragma unroll
        for (int mt = 0; mt < 4; ++mt) {
#pragma unroll
            for (int r = 0; r < 4; ++r) {
                const int row = m0 + wr + mt*16 + quad*4 + r;
                TC* cp = Cb + (long)row * ldc + col;
                float val = alpha * acc[mt][nt][r] + bv;
                if constexpr (RESID) val += ld1c(cp);
                st1c(cp, val);
            }
        }
    }
}

// ---------------------------------------------------------------------------
// Generic MFMA GEMM (validated R8/R9; + CT transposed-store flag):
// C = alpha*(A @ B[^T]) (+bias[biasOff + z*bzStride + col]) (+C) (relu?)
// 64x64 tile/block, 4 waves, 16x16x32 bf16 MFMA, fp32 accumulate.
// XCD-chunked swizzle added (pure index remap, bijective).
// ---------------------------------------------------------------------------
template<class TC, bool BT, bool BIAS, bool RELU, bool RESID, bool CT>
__launch_bounds__(256)
__global__ void gemm_k(const void* __restrict__ A, int cA, long aeOff,
                       const void* __restrict__ B, int cB, long beOff,
                       const void* __restrict__ bias, int cBias, long biasOff, long bzStride,
                       TC* __restrict__ C, const int* __restrict__ flagp,
                       int K, int lda, int ldb, int ldc,
                       long sA, long sB, long sC, float alpha)
{
    const int rtf = *flagp;
    const int fA = (cA == C_RT) ? rtf : cA;
    const int fB = (cB == C_RT) ? rtf : cB;

    const int t = threadIdx.x;
    const int lane = t & 63, wave = t >> 6;
    const int l15 = lane & 15, quad = lane >> 4;

    const int gx = gridDim.x, gy = gridDim.y;
    const int nwg = gx * gy * (int)gridDim.z;
    const int flat = xcd_swz(blockIdx.x + gx * (blockIdx.y + gy * blockIdx.z), nwg);
    const int bx = flat % gx;
    const int by = (flat / gx) % gy;
    const int bz = flat / (gx * gy);

    const int m0 = by * 64, n0 = bx * 64;
    const long z = bz;
    const long aOff = aeOff + z * sA, bOff = beOff + z * sB, cOff = z * sC;

    __shared__ __align__(16) ushortT As[64][40];
    __shared__ __align__(16) ushortT Bs[64][40];

    f32x4 acc[4] = {};

    const int ar = t >> 2, ak = (t & 3) * 8;
    const int bk = t & 31, bn = (t >> 5) * 8;

    for (int k0 = 0; k0 < K; k0 += 32) {
        {
            const long base = aOff + (long)(m0 + ar) * lda + (k0 + ak);
            float4 v0 = get4(A, base, fA);
            float4 v1 = get4(A, base + 4, fA);
            ushortT* dst = &As[ar][ak];
            dst[0]=f2bf(v0.x); dst[1]=f2bf(v0.y); dst[2]=f2bf(v0.z); dst[3]=f2bf(v0.w);
            dst[4]=f2bf(v1.x); dst[5]=f2bf(v1.y); dst[6]=f2bf(v1.z); dst[7]=f2bf(v1.w);
        }
        if constexpr (BT) {
            const long base = bOff + (long)(n0 + ar) * ldb + (k0 + ak);
            float4 v0 = get4(B, base, fB);
            float4 v1 = get4(B, base + 4, fB);
            ushortT* dst = &Bs[ar][ak];
            dst[0]=f2bf(v0.x); dst[1]=f2bf(v0.y); dst[2]=f2bf(v0.z); dst[3]=f2bf(v0.w);
            dst[4]=f2bf(v1.x); dst[5]=f2bf(v1.y); dst[6]=f2bf(v1.z); dst[7]=f2bf(v1.w);
        } else {
            const long base = bOff + (long)(k0 + bk) * ldb + (n0 + bn);
            float4 v0 = get4(B, base, fB);
            float4 v1 = get4(B, base + 4, fB);
            Bs[bn+0][bk] = f2bf(v0.x);
            Bs[bn+1][bk] = f2bf(v0.y);
            Bs[bn+2][bk] = f2bf(v0.z);
            Bs[bn+3][bk] = f2bf(v0.w);
            Bs[bn+4][bk] = f2bf(v1.x);
            Bs[bn+5][bk] = f2bf(v1.y);
            Bs[bn+6][bk] = f2bf(v1.z);
            Bs[bn+7][bk] = f2bf(v1.w);
        }
        __syncthreads();
        const bf16x8 af = *(const bf16x8*)&As[wave*16 + l15][quad*8];
#pragma unroll
        for (int nt = 0; nt < 4; ++nt) {
            const bf16x8 bf = *(const bf16x8*)&Bs[nt*16 + l15][quad*8];
            acc[nt] = __builtin_amdgcn_mfma_f32_16x16x32_bf16(af, bf, acc[nt], 0, 0, 0);
        }
        __syncthreads();
    }

    const int fBias = BIAS ? ((cBias == C_RT) ? rtf : cBias) : 0;
#pragma unroll
    for (int nt = 0; nt < 4; ++nt) {
        const int col = n0 + nt*16 + l15;
        const float bv = BIAS ? get1(bias, biasOff + z*bzStride + col, fBias) : 0.f;
#pragma unroll
        for (int r = 0; r < 4; ++r) {
            const int row = m0 + wave*16 + quad*4 + r;
            TC* cp = CT ? (C + cOff + (long)col * ldc + row)
                        : (C + cOff + (long)row * ldc + col);
            float val = alpha * acc[nt][r] + bv;
            if constexpr (RESID) val += ld1c(cp);
            if constexpr (RELU)  val = fmaxf(val, 0.f);
            st1c(cp, val);
        }
    }
}

// ---------------- block reduction (256 threads) ----------------
__device__ __forceinline__ float blockReduceSum(float v, float* red, int t)
{
    red[t] = v; __syncthreads();
#pragma unroll
    for (int s = 128; s > 0; s >>= 1) {
        if (t < s) red[t] += red[t + s];
        __syncthreads();
    }
    const float r = red[0];
    __syncthreads();
    return r;
}

// ---------------------------------------------------------------------------
// colcomb: out[d] = sum_c v[voff+c] * W[c*1536+d] + b[d]   (f32 out), grid 6x256
// ---------------------------------------------------------------------------
__launch_bounds__(256)
__global__ void colcomb_k(const void* __restrict__ v, int cv, long voff,
                          const void* __restrict__ W, int cW,
                          const void* __restrict__ b, int cb,
                          float* __restrict__ out, const int* __restrict__ flagp)
{
    const int rtf = *flagp;
    const int fv = (cv == C_RT) ? rtf : cv;
    const int fW = (cW == C_RT) ? rtf : cW;
    const int fb = (cb == C_RT) ? rtf : cb;
    const int d = blockIdx.x*256 + threadIdx.x;
    float a0 = 0.f, a1 = 0.f;
    for (int c = 0; c < 1536; c += 2) {
        a0 += get1(v, voff+c+0, fv) * get1(W, (long)(c+0)*1536 + d, fW);
        a1 += get1(v, voff+c+1, fv) * get1(W, (long)(c+1)*1536 + d, fW);
    }
    out[d] = a0 + a1 + get1(b, d, fb);
}

// ---------------------------------------------------------------------------
// rowdot: out[r] = scale * sum_c bf2f(W[r*1536+c]) * v[c]   grid 1536 x 256
// ---------------------------------------------------------------------------
__launch_bounds__(256)
__global__ void rowdot_k(const ushortT* __restrict__ W, const float* __restrict__ v,
                         float* __restrict__ out, float scale)
{
    const int r = blockIdx.x, t = threadIdx.x;
    __shared__ float red[256];
    float p = 0.f;
    for (int c = t; c < 1536; c += 256) p += bf2f(W[(long)r*1536 + c]) * v[c];
    const float tot = blockReduceSum(p, red, t);
    if (t == 0) out[r] = scale * tot;
}

// ---------------------------------------------------------------------------
// gconv1 fused (unchanged — validated)
// ---------------------------------------------------------------------------
__launch_bounds__(256)
__global__ void gconv1_k(int b0, const void* __restrict__ x, const int* __restrict__ edges,
                         const void* __restrict__ ea,
                         const void* __restrict__ wembW, const void* __restrict__ wembB,
                         const void* __restrict__ Wrel, const void* __restrict__ brel,
                         const void* __restrict__ Wroot, ushortT* __restrict__ h1,
                         const int* __restrict__ flagp)
{
    const int f = *flagp;
    const int bl = blockIdx.x, g = b0 + bl, t = threadIdx.x;
    __shared__ float s_x[64][5];
    __shared__ float s_agg[64][5];
    __shared__ int   s_cnt[64];
    __shared__ int   s_off[65];
    __shared__ int   s_src[512];
    __shared__ float s_w[512];

    if (t < 64) s_cnt[t] = 0;
    if (t < 320) s_x[t/5][t%5] = get1(x, (long)(g*64 + t/5)*5 + (t%5), f);
    __syncthreads();

    const float w0 = get1(wembW,0,f), w1 = get1(wembW,1,f), w2 = get1(wembW,2,f);
    const float wb = get1(wembB,0,f);
    int sl[2], dl[2], slot[2]; float wv[2];
#pragma unroll
    for (int e2 = 0; e2 < 2; ++e2) {
        const int e = g*512 + t + 256*e2;
        const int s = edges[e], d = edges[EDIR + e];
        sl[e2] = clampi(s - g*64, 0, 63); dl[e2] = clampi(d - g*64, 0, 63);
        const float a0 = get1(ea, 2L*e, f), a1 = get1(ea, 2L*e+1, f);
        wv[e2] = fmaxf(a0*w0 + ((a1 < 0.5f) ? w1 : w2) + wb, 0.f);
        slot[e2] = atomicAdd(&s_cnt[dl[e2]], 1);
    }
    __syncthreads();
    if (t == 0) {
        int r = 0;
        for (int i = 0; i < 64; ++i) { s_off[i] = r; r += s_cnt[i]; }
        s_off[64] = r;
    }
    __syncthreads();
#pragma unroll
    for (int e2 = 0; e2 < 2; ++e2) {
        const int p = s_off[dl[e2]] + slot[e2];
        s_src[p] = sl[e2]; s_w[p] = wv[e2];
    }
    __syncthreads();
    if (t < 320) {
        const int n = t/5, k = t%5;
        float acc = 0.f;
        for (int i = s_off[n]; i < s_off[n+1]; ++i) acc += s_w[i] * s_x[s_src[i]][k];
        s_agg[n][k] = acc;
    }
    __syncthreads();
    float wr[5], wo[5];
#pragma unroll
    for (int k = 0; k < 5; ++k) { wr[k] = get1(Wrel, k*256 + t, f); wo[k] = get1(Wroot, k*256 + t, f); }
    const float bb = get1(brel, t, f);
    for (int n = 0; n < 64; ++n) {
        float v = bb;
#pragma unroll
        for (int k = 0; k < 5; ++k) v += s_agg[n][k]*wr[k] + s_x[n][k]*wo[k];
        h1[(bl*64 + n)*256 + t] = f2bf(fmaxf(v, 0.f));
    }
}

// ---------------------------------------------------------------------------
// gconv2 aggregation (unchanged — validated)
// ---------------------------------------------------------------------------
__launch_bounds__(256)
__global__ void gconv2_agg_k(int b0, const ushortT* __restrict__ h1, const int* __restrict__ edges,
                             const void* __restrict__ ea,
                             const void* __restrict__ wembW, const void* __restrict__ wembB,
                             ushortT* __restrict__ agg2, const int* __restrict__ flagp)
{
    const int f = *flagp;
    const int bl = blockIdx.x, g = b0 + bl, t = threadIdx.x;
    __shared__ int   s_cnt[64];
    __shared__ int   s_off[65];
    __shared__ int   s_src[512];
    __shared__ float s_w[512];

    if (t < 64) s_cnt[t] = 0;
    __syncthreads();

    const float w0 = get1(wembW,0,f), w1 = get1(wembW,1,f), w2 = get1(wembW,2,f);
    const float wb = get1(wembB,0,f);
    int sl[2], dl[2], slot[2]; float wv[2];
#pragma unroll
    for (int e2 = 0; e2 < 2; ++e2) {
        const int e = g*512 + t + 256*e2;
        const int s = edges[e], d = edges[EDIR + e];
        sl[e2] = clampi(s - g*64, 0, 63); dl[e2] = clampi(d - g*64, 0, 63);
        const float a0 = get1(ea, 2L*e, f), a1 = get1(ea, 2L*e+1, f);
        wv[e2] = fmaxf(a0*w0 + ((a1 < 0.5f) ? w1 : w2) + wb, 0.f);
        slot[e2] = atomicAdd(&s_cnt[dl[e2]], 1);
    }
    __syncthreads();
    if (t == 0) {
        int r = 0;
        for (int i = 0; i < 64; ++i) { s_off[i] = r; r += s_cnt[i]; }
        s_off[64] = r;
    }
    __syncthreads();
#pragma unroll
    for (int e2 = 0; e2 < 2; ++e2) {
        const int p = s_off[dl[e2]] + slot[e2];
        s_src[p] = sl[e2]; s_w[p] = wv[e2];
    }
    __syncthreads();
    for (int n = 0; n < 64; ++n) {
        float acc = 0.f;
        const int i0 = s_off[n], i1 = s_off[n+1];
        for (int i = i0; i < i1; ++i)
            acc += s_w[i] * bf2f(h1[(bl*64 + s_src[i])*256 + t]);
        agg2[(bl*64 + n)*256 + t] = f2bf(acc);
    }
}

// ---------------------------------------------------------------------------
// GraphNorm (unchanged — validated)
// ---------------------------------------------------------------------------
__launch_bounds__(256)
__global__ void gnorm_k(ushortT* __restrict__ h, const void* __restrict__ gw,
                        const void* __restrict__ gb, const void* __restrict__ gms,
                        const int* __restrict__ flagp)
{
    const int f0 = *flagp;
    const int bl = blockIdx.x, t = threadIdx.x;
#pragma unroll
    for (int f2 = 0; f2 < 2; ++f2) {
        const int f = t + 256*f2;
        float acc = 0.f;
        for (int n = 0; n < 64; ++n) acc += bf2f(h[(bl*64+n)*512 + f]);
        const float m2 = get1(gms, f, f0) * (acc * (1.f/64.f));
        float v = 0.f;
        for (int n = 0; n < 64; ++n) { const float d = bf2f(h[(bl*64+n)*512 + f]) - m2; v += d*d; }
        const float rs = rsqrtf(v*(1.f/64.f) + EPSC);
        const float g = get1(gw, f, f0), bb = get1(gb, f, f0);
        for (int n = 0; n < 64; ++n) {
            const int idx = (bl*64+n)*512 + f;
            h[idx] = f2bf(g * (bf2f(h[idx]) - m2) * rs + bb);
        }
    }
}

// ---------------------------------------------------------------------------
// SplitSyndromes sort (unchanged — validated)
// ---------------------------------------------------------------------------
__launch_bounds__(256)
__global__ void sort_k(const int* __restrict__ edges, int* __restrict__ sorted_orig,
                       int* __restrict__ se, int* __restrict__ te)
{
    const int b = blockIdx.x, t = threadIdx.x;
    __shared__ int s_keep[512];
    __shared__ int s_key[512];
    __shared__ int s_ckey[256];
    __shared__ int s_corig[256];
#pragma unroll
    for (int e2 = 0; e2 < 2; ++e2) {
        const int el = t + 256*e2;
        const int e = b*512 + el;
        const int s = edges[e], d = edges[EDIR + e];
        s_keep[el] = (s > d) ? 1 : 0;
        s_key[el]  = ((s - b*64) << 6) | (d - b*64);
    }
    __syncthreads();
#pragma unroll
    for (int e2 = 0; e2 < 2; ++e2) {
        const int el = t + 256*e2;
        if (s_keep[el]) {
            int pos = 0;
            for (int j = 0; j < el; ++j) pos += s_keep[j];
            s_ckey[pos]  = s_key[el];
            s_corig[pos] = b*512 + el;
        }
    }
    __syncthreads();
    const int ki = s_ckey[t];
    int rank = 0;
    for (int j = 0; j < 256; ++j) {
        const int kj = s_ckey[j];
        rank += (kj < ki || (kj == ki && j < t)) ? 1 : 0;
    }
    const int orig = s_corig[t];
    const int p = b*256 + rank;
    sorted_orig[p] = orig;
    se[p] = edges[orig];
    te[p] = edges[EDIR + orig];
}

// ---------------------------------------------------------------------------
// Build F_c + bvec[ge] = F[e] . kb  (unchanged — validated)
// ---------------------------------------------------------------------------
__launch_bounds__(256)
__global__ void fbuild_k(int b0, int maxn, const ushortT* __restrict__ h,
                         const int* __restrict__ sorted_orig,
                         const int* __restrict__ se, const int* __restrict__ te,
                         const void* __restrict__ ea,
                         const void* __restrict__ eW, const void* __restrict__ eB,
                         const float* __restrict__ kb,
                         ushortT* __restrict__ F, float* __restrict__ bvec,
                         const int* __restrict__ flagp)
{
    const int fl = *flagp;
    const int e = blockIdx.x, t = threadIdx.x;
    __shared__ float red[256];
    const int ge = b0*256 + e;
    const int s = clampi(se[ge] - b0*64, 0, maxn);
    const int d = clampi(te[ge] - b0*64, 0, maxn);
    const int orig = clampi(sorted_orig[ge], 0, EDIR-1);
    const float a0 = get1(ea, 2L*orig, fl), a1 = get1(ea, 2L*orig + 1, fl);
    float partial = 0.f;
#pragma unroll
    for (int c = 0; c < 6; ++c) {
        const int col = c*256 + t;
        float v;
        if (c < 2) {
            v = bf2f(h[(long)s*512 + col]);
        } else if (c < 4) {
            const int ff = col - 512;
            v = fmaxf(a0*get1(eW, ff, fl)
                      + ((a1 < 0.5f) ? get1(eW, 512+ff, fl) : get1(eW, 1024+ff, fl))
                      + get1(eB, ff, fl), 0.f);
        } else {
            v = bf2f(h[(long)d*512 + (col - 1024)]);
        }
        F[(long)e*1536 + col] = f2bf(v);
        partial += v * kb[col];
    }
    const float tot = blockReduceSum(partial, red, t);
    if (t == 0) bvec[ge] = tot;
}

// ---------------- row softmax (unchanged — validated) ----------------
__launch_bounds__(256)
__global__ void softmax_k(float* __restrict__ S)
{
    const long row = blockIdx.x;
    const int t = threadIdx.x;
    __shared__ float red[256];
    const float v = S[row*256 + t];
    red[t] = v; __syncthreads();
#pragma unroll
    for (int s = 128; s > 0; s >>= 1) { if (t < s) red[t] = fmaxf(red[t], red[t+s]); __syncthreads(); }
    const float mx = red[0]; __syncthreads();
    const float e = __expf(v - mx);
    red[t] = e; __syncthreads();
#pragma unroll
    for (int s = 128; s > 0; s >>= 1) { if (t < s) red[t] += red[t+s]; __syncthreads(); }
    const float sum = red[0];
    S[row*256 + t] = e / sum;
}

// ---------------- fused LayerNorm + head dot (unchanged — validated) --------
__launch_bounds__(256)
__global__ void ln_head_k(int b0, const ushortT* __restrict__ F, const void* __restrict__ lng,
                          const void* __restrict__ lnb, const void* __restrict__ hW,
                          const void* __restrict__ hB, float* __restrict__ gout,
                          const int* __restrict__ flagp)
{
    const int fl = *flagp;
    const int e = blockIdx.x, t = threadIdx.x;
    __shared__ float red[256];
    float xv[6];
    float s = 0.f;
#pragma unroll
    for (int c = 0; c < 6; ++c) { xv[c] = bf2f(F[(long)e*1536 + c*256 + t]); s += xv[c]; }
    const float tot = blockReduceSum(s, red, t);
    const float mu = tot * (1.f/1536.f);
    float ss = 0.f;
#pragma unroll
    for (int c = 0; c < 6; ++c) { const float d = xv[c] - mu; ss += d*d; }
    const float tot2 = blockReduceSum(ss, red, t);
    const float rs = rsqrtf(tot2 * (1.f/1536.f) + EPSC);
    float p = 0.f;
#pragma unroll
    for (int c = 0; c < 6; ++c) {
        const int col = c*256 + t;
        p += (get1(lng, col, fl) * (xv[c] - mu) * rs + get1(lnb, col, fl)) * get1(hW, col, fl);
    }
    const float tot3 = blockReduceSum(p, red, t);
    if (t == 0) gout[b0*256 + e] = tot3 + get1(hB, 0, fl);
}

// ---------------- final output assembly (unchanged — validated) -------------
__launch_bounds__(128)
__global__ void final_k(const float* __restrict__ gout, const int* __restrict__ se,
                        const int* __restrict__ te, const int* __restrict__ sorted_orig,
                        const void* __restrict__ ea, float* __restrict__ out,
                        const int* __restrict__ flagp)
{
    const int fl = *flagp;
    const int b = blockIdx.x, j = threadIdx.x;
    const int e0 = b*256 + 2*j, e1 = e0 + 1;
    const float p0 = gout[e0], p1 = gout[e1];
    const int idx = (p1 < p0) ? 1 : 0;
    const float val = idx ? p1 : p0;
    const int eo = idx ? e1 : e0;
    const int orig = clampi(sorted_orig[eo], 0, EDIR-1);
    const float cls = get1(ea, 2L*orig + 1, fl);
    out[(b*128 + j)*2 + 0] = (float)se[e0];
    out[(b*128 + j)*2 + 1] = (float)te[e0];
    out[32768 + b*128 + j] = val;
    out[32768 + 16384 + b*128 + j] = cls;
}

// ---------------------------------------------------------------------------
// Launch: phase-W precombination emits MpT/WvoT (transposed, bf16) so the hot
// GEMMs run on the fast k-contiguous bf16 path.
// ---------------------------------------------------------------------------
extern "C" void kernel_launch(void* const* d_in, const int* in_sizes, int n_in,
                              void* d_out, int out_size, void* d_ws, size_t ws_size,
                              hipStream_t stream)
{
    (void)out_size;

    const void* x     = d_in[0];
    const int*  edges = (const int*)d_in[1];
    const void* ea    = d_in[2];

    int ws0 = 3;
    while (ws0 < n_in && in_sizes[ws0] != 3) ++ws0;
    if (ws0 + 27 > n_in) ws0 = 5;

    const void* wembW  = d_in[ws0 + 0];
    const void* wembB  = d_in[ws0 + 1];
    const void* g1Wrel = d_in[ws0 + 2];
    const void* g1brel = d_in[ws0 + 3];
    const void* g1Wroot= d_in[ws0 + 4];
    const void* g2Wrel = d_in[ws0 + 5];
    const void* g2brel = d_in[ws0 + 6];
    const void* g2Wroot= d_in[ws0 + 7];
    const void* gnw    = d_in[ws0 + 8];
    const void* gnb    = d_in[ws0 + 9];
    const void* gnms   = d_in[ws0 + 10];
    const void* eembW  = d_in[ws0 + 11];
    const void* eembB  = d_in[ws0 + 12];
    const void* qkvW   = d_in[ws0 + 13];
    const void* qkvb   = d_in[ws0 + 14];
    const void* inWq   = d_in[ws0 + 15];
    const void* inWk   = d_in[ws0 + 16];
    const void* inWv   = d_in[ws0 + 17];
    const void* inbq   = d_in[ws0 + 18];
    // inbk (ws0+19): row-constant score terms -> drop in softmax
    const void* inbv   = d_in[ws0 + 20];
    const void* outW   = d_in[ws0 + 21];
    const void* outb   = d_in[ws0 + 22];
    const void* lng    = d_in[ws0 + 23];
    const void* lnb    = d_in[ws0 + 24];
    const void* headW  = d_in[ws0 + 25];
    const void* headb  = d_in[ws0 + 26];

    char* ws = (char*)d_ws;
    size_t off = 0;
    auto alloc = [&](size_t bytes) {
        void* p = ws + off;
        off = (off + bytes + 255) & ~(size_t)255;
        return p;
    };
    // ---- fixed region (~10.6 MB) ----
    int*     dflag  = (int*)    alloc(256);
    float*   gout   = (float*)  alloc(EKEEP*4);
    int*     sorted = (int*)    alloc(EKEEP*4);
    int*     seg    = (int*)    alloc(EKEEP*4);
    int*     teg    = (int*)    alloc(EKEEP*4);
    float*   bvec   = (float*)  alloc(EKEEP*4);
    float*   bqc    = (float*)  alloc(1536*4);
    float*   bvc    = (float*)  alloc(1536*4);
    float*   kb     = (float*)  alloc(1536*4);
    float*   bvo    = (float*)  alloc(1536*4);
    ushortT* MpT    = (ushortT*)alloc(1536L*1536*2);   // Mp^T, [n][k]
    ushortT* WvoT   = (ushortT*)alloc(1536L*1536*2);   // Wvo^T, [n][k]
    const size_t fixedB = off;

    // union region: phase-W (Wqc|Wkc, Wvc reuses Wqc) vs chunk scratch
    char* uni = ws + off;
    ushortT* Wqc = (ushortT*)uni;
    ushortT* Wkc = (ushortT*)(uni + ((1536L*1536*2 + 255) & ~255L));
    ushortT* Wvc = Wqc;

    const size_t perG = 64L*512*2 + 2L*64*256*2 + 2L*256*1536*2 + 256L*256*4; // 1.97MB
    int G = 128;
    while (G > 1 && fixedB + (size_t)G*perG + 8192 > ws_size) G >>= 1;

    size_t coff = fixedB;
    auto calloc2 = [&](size_t bytes) {
        void* p = ws + coff;
        coff = (coff + bytes + 255) & ~(size_t)255;
        return p;
    };
    ushortT* h_c  = (ushortT*)calloc2((size_t)G*64*512*2);
    ushortT* h1_c = (ushortT*)calloc2((size_t)G*64*256*2);
    ushortT* ag_c = (ushortT*)calloc2((size_t)G*64*256*2);
    ushortT* F_c  = (ushortT*)calloc2((size_t)G*256*1536*2);
    ushortT* T_c  = (ushortT*)calloc2((size_t)G*256*1536*2);
    float*   S_c  = (float*)  calloc2((size_t)G*256*256*4);

    const float scale = 0.02551551815399144f;  // 1/sqrt(1536)
    const dim3 blk(256);

    detect_k<<<1, blk, 0, stream>>>((const unsigned int*)x, dflag);
    sort_k<<<128, blk, 0, stream>>>(edges, sorted, seg, teg);

    // ---- phase W: weight precombination ----
    gemm_k<ushortT,false,false,false,false,false><<<dim3(24,24,1), blk, 0, stream>>>(
        qkvW, C_RT, 0, inWq, C_RT, 0, (const void*)nullptr, C_BF, 0, 0,
        Wqc, dflag, 1536, 4608, 1536, 1536, 0,0,0, 1.f);
    gemm_k<ushortT,false,false,false,false,false><<<dim3(24,24,1), blk, 0, stream>>>(
        qkvW, C_RT, 1536, inWk, C_RT, 0, (const void*)nullptr, C_BF, 0, 0,
        Wkc, dflag, 1536, 4608, 1536, 1536, 0,0,0, 1.f);
    colcomb_k<<<6, blk, 0, stream>>>(qkvb, C_RT, 0, inWq, C_RT, inbq, C_RT, bqc, dflag);
    // MpT = scale * Wkc @ Wqc^T   (Mp^T directly — operands swapped)
    gemm_k<ushortT,true,false,false,false,false><<<dim3(24,24,1), blk, 0, stream>>>(
        Wkc, C_BF, 0, Wqc, C_BF, 0, (const void*)nullptr, C_BF, 0, 0,
        MpT, dflag, 1536, 1536, 1536, 1536, 0,0,0, scale);
    // kb = scale * Wkc @ bqc
    rowdot_k<<<1536, blk, 0, stream>>>(Wkc, bqc, kb, scale);
    // Wvc = qkvW[:,3072:4608] @ inWv  (reuses Wqc slot)
    gemm_k<ushortT,false,false,false,false,false><<<dim3(24,24,1), blk, 0, stream>>>(
        qkvW, C_RT, 3072, inWv, C_RT, 0, (const void*)nullptr, C_BF, 0, 0,
        Wvc, dflag, 1536, 4608, 1536, 1536, 0,0,0, 1.f);
    colcomb_k<<<6, blk, 0, stream>>>(qkvb, C_RT, 3072, inWv, C_RT, inbv, C_RT, bvc, dflag);
    // WvoT = (Wvc @ outW)^T  via transposed store
    gemm_k<ushortT,false,false,false,false,true><<<dim3(24,24,1), blk, 0, stream>>>(
        Wvc, C_BF, 0, outW, C_RT, 0, (const void*)nullptr, C_BF, 0, 0,
        WvoT, dflag, 1536, 1536, 1536, 1536, 0,0,0, 1.f);
    colcomb_k<<<6, blk, 0, stream>>>(bvc, C_F32, 0, outW, C_RT, outb, C_RT, bvo, dflag);

    // ---- per-chunk pipeline ----
    const int nchunk = 128 / G;
    const int EC = G * 256;
    for (int c = 0; c < nchunk; ++c) {
        const int b0 = c * G;
        gconv1_k<<<G, blk, 0, stream>>>(b0, x, edges, ea, wembW, wembB,
                                        g1Wrel, g1brel, g1Wroot, h1_c, dflag);
        gconv2_agg_k<<<G, blk, 0, stream>>>(b0, h1_c, edges, ea, wembW, wembB, ag_c, dflag);
        gemm_k<ushortT,false,true,false,false,false><<<dim3(8,G,1), blk, 0, stream>>>(
            ag_c, C_BF, 0, g2Wrel, C_RT, 0, g2brel, C_RT, 0, 0, h_c, dflag,
            256, 256, 512, 512, 0,0,0, 1.f);
        gemm_k<ushortT,false,false,true,true,false><<<dim3(8,G,1), blk, 0, stream>>>(
            h1_c, C_BF, 0, g2Wroot, C_RT, 0, (const void*)nullptr, C_BF, 0, 0, h_c, dflag,
            256, 256, 512, 512, 0,0,0, 1.f);
        gnorm_k<<<G, blk, 0, stream>>>(h_c, gnw, gnb, gnms, dflag);
        fbuild_k<<<EC, blk, 0, stream>>>(b0, G*64-1, h_c, sorted, seg, teg, ea,
                                         eembW, eembB, kb, F_c, bvec, dflag);
        // T = F @ MpT^T   (fast bf16 path)
        bgemm_k<ushortT,false,false><<<dim3(12, EC/128, 1), blk, 0, stream>>>(
            F_c, MpT, nullptr, T_c, 1536, 1536, 1536, 1536, 0,0,0, 0,0, 1.f);
        // S_b = T_b @ F_b^T + bvec
        bgemm_k<float,true,false><<<dim3(2, 2, G), blk, 0, stream>>>(
            T_c, F_c, bvec + (long)b0*256, S_c, 1536, 1536, 1536, 256,
            256L*1536, 256L*1536, 65536L, 0, 256, 1.f);
        softmax_k<<<EC, blk, 0, stream>>>(S_c);
        // R_b = P_b @ F_b  -> T_c (generic path: A is f32)
        gemm_k<ushortT,false,false,false,false,false><<<dim3(24,4,G), blk, 0, stream>>>(
            S_c, C_F32, 0, F_c, C_BF, 0, (const void*)nullptr, C_BF, 0, 0, T_c, dflag,
            256, 256, 1536, 1536, 65536L, 256L*1536, 256L*1536, 1.f);
        // F += R @ WvoT^T + bvo   (fast bf16 path, residual)
        bgemm_k<ushortT,true,true><<<dim3(12, EC/128, 1), blk, 0, stream>>>(
            T_c, WvoT, bvo, F_c, 1536, 1536, 1536, 1536, 0,0,0, 0,0, 1.f);
        ln_head_k<<<EC, blk, 0, stream>>>(b0, F_c, lng, lnb, headW, headb, gout, dflag);
    }

    final_k<<<128, dim3(128), 0, stream>>>(gout, seg, teg, sorted, ea, (float*)d_out, dflag);
}

// Round 3
// 1426.886 us; speedup vs baseline: 1.7161x; 1.5958x over previous
//
#include <hip/hip_runtime.h>
#include <math.h>

// Problem constants
#define NTOT   8192
#define BGR    128
#define NPER   64
#define EDIR   65536
#define EKEEP  32768
#define EPSC   1e-5f

typedef unsigned short ushortT;
typedef __attribute__((ext_vector_type(8))) short bf16x8;
typedef __attribute__((ext_vector_type(4))) float f32x4;

// Operand dtype codes: 0 = bf16, 1 = f32, 2 = runtime (read *flagp)
#define C_BF 0
#define C_F32 1
#define C_RT 2

// ---------------- dtype helpers ----------------
__device__ __forceinline__ float bf2f(ushortT u) {
    union { unsigned int i; float f; } v; v.i = ((unsigned int)u) << 16; return v.f;
}
__device__ __forceinline__ ushortT f2bf(float f) {
    unsigned int u = __float_as_uint(f);
    u += 0x7FFFu + ((u >> 16) & 1u);   // round to nearest even
    return (ushortT)(u >> 16);
}
__device__ __forceinline__ float get1(const void* p, long i, int f) {
    return f ? ((const float*)p)[i] : bf2f(((const ushortT*)p)[i]);
}
__device__ __forceinline__ float4 get4(const void* p, long i, int f) {
    if (f) return *(const float4*)((const float*)p + i);
    ushort4 u = *(const ushort4*)((const ushortT*)p + i);
    return make_float4(bf2f(u.x), bf2f(u.y), bf2f(u.z), bf2f(u.w));
}
__device__ __forceinline__ float ld1c(const float* p)   { return *p; }
__device__ __forceinline__ float ld1c(const ushortT* p) { return bf2f(*p); }
__device__ __forceinline__ void st1c(float* p, float v)   { *p = v; }
__device__ __forceinline__ void st1c(ushortT* p, float v) { *p = f2bf(v); }
__device__ __forceinline__ int clampi(int v, int lo, int hi) {
    return v < lo ? lo : (v > hi ? hi : v);
}

// direct global->LDS DMA, 16B per lane (lane-linear LDS destination required)
__device__ __forceinline__ void gld16(const void* g, void* l) {
    __builtin_amdgcn_global_load_lds(
        (const __attribute__((address_space(1))) unsigned int*)g,
        (__attribute__((address_space(3))) unsigned int*)l, 16, 0, 0);
}

// Bijective XCD-chunked block-id swizzle (m204): hardware blocks round-robin
// XCDs by flat%8; remap so each XCD owns a CONTIGUOUS chunk of work ids ->
// blocks sharing operand panels co-reside in one XCD's L2.
__device__ __forceinline__ int xcd_swz(int flat, int nwg) {
    const int q = nwg >> 3, r = nwg & 7;
    const int xcd = flat & 7, idx = flat >> 3;
    return (xcd < r ? xcd * (q + 1) : r * (q + 1) + (xcd - r) * q) + idx;
}

// ---------------------------------------------------------------------------
// Float-input dtype detector (validated R7-R9).
// ---------------------------------------------------------------------------
__launch_bounds__(256)
__global__ void detect_k(const unsigned int* __restrict__ xw, int* __restrict__ flag)
{
    __shared__ int red[256];
    const int t = threadIdx.x;
    int hits = 0;
#pragma unroll
    for (int i = 0; i < 4; ++i) {
        const unsigned w = xw[t*4 + i];
        const unsigned eb = (w >> 7) & 0xFF;
        hits += (eb >= 100 && eb <= 150) ? 1 : 0;
    }
    red[t] = hits; __syncthreads();
#pragma unroll
    for (int s = 128; s > 0; s >>= 1) { if (t < s) red[t] += red[t+s]; __syncthreads(); }
    if (t == 0) *flag = (red[0] < 512) ? 1 : 0;
}

// ---------------------------------------------------------------------------
// Fast bf16 GEMM: C = alpha*(A @ B^T) (+bias f32) (+C). Both A and B read
// k-contiguous (B stored [n][k]). 128x128 tile/block, 4 waves (2x2), each
// wave 64x64 via 4x4 16x16x32 bf16 MFMA tiles, BK=32, fp32 accumulate.
// m97 structure: global_load_lds width=16 staging into linear [128][32] LDS,
// 2 barriers / K-step. XCD-chunked swizzle for per-XCD L2 operand locality.
// Requires M%128==0 (per batch), N%128==0, K%32==0, lda/ldb%8==0.
// ---------------------------------------------------------------------------
template<class TC, bool BIAS, bool RESID>
__launch_bounds__(256)
__global__ void bgemm_k(const ushortT* __restrict__ A, const ushortT* __restrict__ B,
                        const float* __restrict__ bias, TC* __restrict__ C,
                        int K, int lda, int ldb, int ldc,
                        long sA, long sB, long sC, long biasOff, long bzStride,
                        float alpha)
{
    const int t = threadIdx.x;
    const int lane = t & 63, wave = t >> 6;
    const int l15 = lane & 15, quad = lane >> 4;
    const int wr = (wave >> 1) * 64, wc = (wave & 1) * 64;

    // XCD-chunked remap of the flattened grid (bijective)
    const int gx = gridDim.x, gy = gridDim.y;
    const int nwg = gx * gy * (int)gridDim.z;
    const int flat = xcd_swz(blockIdx.x + gx * (blockIdx.y + gy * blockIdx.z), nwg);
    const int bx = flat % gx;
    const int by = (flat / gx) % gy;
    const int bz = flat / (gx * gy);

    const int m0 = by * 128, n0 = bx * 128;
    const long z = bz;

    __shared__ __align__(16) ushortT As[128][32];   // linear: no pad (gload_lds)
    __shared__ __align__(16) ushortT Bs[128][32];

    f32x4 acc[4][4] = {};

    const int sr = t >> 2, sk = (t & 3) * 8;   // staging: 64 rows/issue, 16B/thread
    const ushortT* pA0 = A + z*sA + (long)(m0 + sr) * lda + sk;
    const ushortT* pA1 = pA0 + 64L * lda;
    const ushortT* pB0 = B + z*sB + (long)(n0 + sr) * ldb + sk;
    const ushortT* pB1 = pB0 + 64L * ldb;
    ushortT* lA0 = &As[sr][sk];
    ushortT* lA1 = &As[64 + sr][sk];
    ushortT* lB0 = &Bs[sr][sk];
    ushortT* lB1 = &Bs[64 + sr][sk];

    for (int k0 = 0; k0 < K; k0 += 32) {
        gld16(pA0 + k0, lA0);
        gld16(pA1 + k0, lA1);
        gld16(pB0 + k0, lB0);
        gld16(pB1 + k0, lB1);
        __syncthreads();   // compiler emits vmcnt(0) drain before s_barrier
        bf16x8 af[4], bfr[4];
#pragma unroll
        for (int i = 0; i < 4; ++i) {
            af[i]  = *(const bf16x8*)&As[wr + i*16 + l15][quad*8];
            bfr[i] = *(const bf16x8*)&Bs[wc + i*16 + l15][quad*8];
        }
#pragma unroll
        for (int mt = 0; mt < 4; ++mt)
#pragma unroll
            for (int nt = 0; nt < 4; ++nt)
                acc[mt][nt] = __builtin_amdgcn_mfma_f32_16x16x32_bf16(af[mt], bfr[nt], acc[mt][nt], 0, 0, 0);
        __syncthreads();
    }

    TC* Cb = C + z * sC;
#pragma unroll
    for (int nt = 0; nt < 4; ++nt) {
        const int col = n0 + wc + nt*16 + l15;
        const float bv = BIAS ? bias[biasOff + z*bzStride + col] : 0.f;
#pragma unroll
        for (int mt = 0; mt < 4; ++mt) {
#pragma unroll
            for (int r = 0; r < 4; ++r) {
                const int row = m0 + wr + mt*16 + quad*4 + r;
                TC* cp = Cb + (long)row * ldc + col;
                float val = alpha * acc[mt][nt][r] + bv;
                if constexpr (RESID) val += ld1c(cp);
                st1c(cp, val);
            }
        }
    }
}

// ---------------------------------------------------------------------------
// Generic MFMA GEMM (validated R8/R9; + CT transposed-store flag):
// C = alpha*(A @ B[^T]) (+bias[biasOff + z*bzStride + col]) (+C) (relu?)
// 64x64 tile/block, 4 waves, 16x16x32 bf16 MFMA, fp32 accumulate.
// XCD-chunked swizzle added (pure index remap, bijective).
// ---------------------------------------------------------------------------
template<class TC, bool BT, bool BIAS, bool RELU, bool RESID, bool CT>
__launch_bounds__(256)
__global__ void gemm_k(const void* __restrict__ A, int cA, long aeOff,
                       const void* __restrict__ B, int cB, long beOff,
                       const void* __restrict__ bias, int cBias, long biasOff, long bzStride,
                       TC* __restrict__ C, const int* __restrict__ flagp,
                       int K, int lda, int ldb, int ldc,
                       long sA, long sB, long sC, float alpha)
{
    const int rtf = *flagp;
    const int fA = (cA == C_RT) ? rtf : cA;
    const int fB = (cB == C_RT) ? rtf : cB;

    const int t = threadIdx.x;
    const int lane = t & 63, wave = t >> 6;
    const int l15 = lane & 15, quad = lane >> 4;

    const int gx = gridDim.x, gy = gridDim.y;
    const int nwg = gx * gy * (int)gridDim.z;
    const int flat = xcd_swz(blockIdx.x + gx * (blockIdx.y + gy * blockIdx.z), nwg);
    const int bx = flat % gx;
    const int by = (flat / gx) % gy;
    const int bz = flat / (gx * gy);

    const int m0 = by * 64, n0 = bx * 64;
    const long z = bz;
    const long aOff = aeOff + z * sA, bOff = beOff + z * sB, cOff = z * sC;

    __shared__ __align__(16) ushortT As[64][40];
    __shared__ __align__(16) ushortT Bs[64][40];

    f32x4 acc[4] = {};

    const int ar = t >> 2, ak = (t & 3) * 8;
    const int bk = t & 31, bn = (t >> 5) * 8;

    for (int k0 = 0; k0 < K; k0 += 32) {
        {
            const long base = aOff + (long)(m0 + ar) * lda + (k0 + ak);
            float4 v0 = get4(A, base, fA);
            float4 v1 = get4(A, base + 4, fA);
            ushortT* dst = &As[ar][ak];
            dst[0]=f2bf(v0.x); dst[1]=f2bf(v0.y); dst[2]=f2bf(v0.z); dst[3]=f2bf(v0.w);
            dst[4]=f2bf(v1.x); dst[5]=f2bf(v1.y); dst[6]=f2bf(v1.z); dst[7]=f2bf(v1.w);
        }
        if constexpr (BT) {
            const long base = bOff + (long)(n0 + ar) * ldb + (k0 + ak);
            float4 v0 = get4(B, base, fB);
            float4 v1 = get4(B, base + 4, fB);
            ushortT* dst = &Bs[ar][ak];
            dst[0]=f2bf(v0.x); dst[1]=f2bf(v0.y); dst[2]=f2bf(v0.z); dst[3]=f2bf(v0.w);
            dst[4]=f2bf(v1.x); dst[5]=f2bf(v1.y); dst[6]=f2bf(v1.z); dst[7]=f2bf(v1.w);
        } else {
            const long base = bOff + (long)(k0 + bk) * ldb + (n0 + bn);
            float4 v0 = get4(B, base, fB);
            float4 v1 = get4(B, base + 4, fB);
            Bs[bn+0][bk] = f2bf(v0.x);
            Bs[bn+1][bk] = f2bf(v0.y);
            Bs[bn+2][bk] = f2bf(v0.z);
            Bs[bn+3][bk] = f2bf(v0.w);
            Bs[bn+4][bk] = f2bf(v1.x);
            Bs[bn+5][bk] = f2bf(v1.y);
            Bs[bn+6][bk] = f2bf(v1.z);
            Bs[bn+7][bk] = f2bf(v1.w);
        }
        __syncthreads();
        const bf16x8 af = *(const bf16x8*)&As[wave*16 + l15][quad*8];
#pragma unroll
        for (int nt = 0; nt < 4; ++nt) {
            const bf16x8 bf = *(const bf16x8*)&Bs[nt*16 + l15][quad*8];
            acc[nt] = __builtin_amdgcn_mfma_f32_16x16x32_bf16(af, bf, acc[nt], 0, 0, 0);
        }
        __syncthreads();
    }

    const int fBias = BIAS ? ((cBias == C_RT) ? rtf : cBias) : 0;
#pragma unroll
    for (int nt = 0; nt < 4; ++nt) {
        const int col = n0 + nt*16 + l15;
        const float bv = BIAS ? get1(bias, biasOff + z*bzStride + col, fBias) : 0.f;
#pragma unroll
        for (int r = 0; r < 4; ++r) {
            const int row = m0 + wave*16 + quad*4 + r;
            TC* cp = CT ? (C + cOff + (long)col * ldc + row)
                        : (C + cOff + (long)row * ldc + col);
            float val = alpha * acc[nt][r] + bv;
            if constexpr (RESID) val += ld1c(cp);
            if constexpr (RELU)  val = fmaxf(val, 0.f);
            st1c(cp, val);
        }
    }
}

// ---------------- block reduction (256 threads) ----------------
__device__ __forceinline__ float blockReduceSum(float v, float* red, int t)
{
    red[t] = v; __syncthreads();
#pragma unroll
    for (int s = 128; s > 0; s >>= 1) {
        if (t < s) red[t] += red[t + s];
        __syncthreads();
    }
    const float r = red[0];
    __syncthreads();
    return r;
}

// ---------------------------------------------------------------------------
// colcomb split (R2): out[d] = sum_c v[voff+c]*W[c*1536+d] + b[d].
// Old single-kernel version ran at grid=6 -> 24 waves, latency-serialized,
// 308 us each (3 per iter = 40% of runtime, hbm 15 GB/s). Split the
// c-reduction across 64 blocks (grid 6x64, 384 blocks) writing partials,
// then a deterministic fixed-order reduce adds bias. No atomics.
// ---------------------------------------------------------------------------
__launch_bounds__(256)
__global__ void colcomb_part_k(const void* __restrict__ v, int cv, long voff,
                               const void* __restrict__ W, int cW,
                               float* __restrict__ part, const int* __restrict__ flagp)
{
    const int rtf = *flagp;
    const int fv = (cv == C_RT) ? rtf : cv;
    const int fW = (cW == C_RT) ? rtf : cW;
    const int d = blockIdx.x*256 + threadIdx.x;
    const int c0 = blockIdx.y * 24;
    float a = 0.f;
#pragma unroll
    for (int i = 0; i < 24; ++i) {
        const int c = c0 + i;
        a += get1(v, voff + c, fv) * get1(W, (long)c*1536 + d, fW);
    }
    part[blockIdx.y * 1536 + d] = a;
}

__launch_bounds__(256)
__global__ void colcomb_red_k(const float* __restrict__ part,
                              const void* __restrict__ b, int cb,
                              float* __restrict__ out, const int* __restrict__ flagp)
{
    const int rtf = *flagp;
    const int fb = (cb == C_RT) ? rtf : cb;
    const int d = blockIdx.x*256 + threadIdx.x;
    float a = get1(b, d, fb);
#pragma unroll 8
    for (int cy = 0; cy < 64; ++cy) a += part[cy*1536 + d];
    out[d] = a;
}

// ---------------------------------------------------------------------------
// rowdot: out[r] = scale * sum_c bf2f(W[r*1536+c]) * v[c]   grid 1536 x 256
// ---------------------------------------------------------------------------
__launch_bounds__(256)
__global__ void rowdot_k(const ushortT* __restrict__ W, const float* __restrict__ v,
                         float* __restrict__ out, float scale)
{
    const int r = blockIdx.x, t = threadIdx.x;
    __shared__ float red[256];
    float p = 0.f;
    for (int c = t; c < 1536; c += 256) p += bf2f(W[(long)r*1536 + c]) * v[c];
    const float tot = blockReduceSum(p, red, t);
    if (t == 0) out[r] = scale * tot;
}

// ---------------------------------------------------------------------------
// gconv1 fused (unchanged — validated)
// ---------------------------------------------------------------------------
__launch_bounds__(256)
__global__ void gconv1_k(int b0, const void* __restrict__ x, const int* __restrict__ edges,
                         const void* __restrict__ ea,
                         const void* __restrict__ wembW, const void* __restrict__ wembB,
                         const void* __restrict__ Wrel, const void* __restrict__ brel,
                         const void* __restrict__ Wroot, ushortT* __restrict__ h1,
                         const int* __restrict__ flagp)
{
    const int f = *flagp;
    const int bl = blockIdx.x, g = b0 + bl, t = threadIdx.x;
    __shared__ float s_x[64][5];
    __shared__ float s_agg[64][5];
    __shared__ int   s_cnt[64];
    __shared__ int   s_off[65];
    __shared__ int   s_src[512];
    __shared__ float s_w[512];

    if (t < 64) s_cnt[t] = 0;
    if (t < 320) s_x[t/5][t%5] = get1(x, (long)(g*64 + t/5)*5 + (t%5), f);
    __syncthreads();

    const float w0 = get1(wembW,0,f), w1 = get1(wembW,1,f), w2 = get1(wembW,2,f);
    const float wb = get1(wembB,0,f);
    int sl[2], dl[2], slot[2]; float wv[2];
#pragma unroll
    for (int e2 = 0; e2 < 2; ++e2) {
        const int e = g*512 + t + 256*e2;
        const int s = edges[e], d = edges[EDIR + e];
        sl[e2] = clampi(s - g*64, 0, 63); dl[e2] = clampi(d - g*64, 0, 63);
        const float a0 = get1(ea, 2L*e, f), a1 = get1(ea, 2L*e+1, f);
        wv[e2] = fmaxf(a0*w0 + ((a1 < 0.5f) ? w1 : w2) + wb, 0.f);
        slot[e2] = atomicAdd(&s_cnt[dl[e2]], 1);
    }
    __syncthreads();
    if (t == 0) {
        int r = 0;
        for (int i = 0; i < 64; ++i) { s_off[i] = r; r += s_cnt[i]; }
        s_off[64] = r;
    }
    __syncthreads();
#pragma unroll
    for (int e2 = 0; e2 < 2; ++e2) {
        const int p = s_off[dl[e2]] + slot[e2];
        s_src[p] = sl[e2]; s_w[p] = wv[e2];
    }
    __syncthreads();
    if (t < 320) {
        const int n = t/5, k = t%5;
        float acc = 0.f;
        for (int i = s_off[n]; i < s_off[n+1]; ++i) acc += s_w[i] * s_x[s_src[i]][k];
        s_agg[n][k] = acc;
    }
    __syncthreads();
    float wr[5], wo[5];
#pragma unroll
    for (int k = 0; k < 5; ++k) { wr[k] = get1(Wrel, k*256 + t, f); wo[k] = get1(Wroot, k*256 + t, f); }
    const float bb = get1(brel, t, f);
    for (int n = 0; n < 64; ++n) {
        float v = bb;
#pragma unroll
        for (int k = 0; k < 5; ++k) v += s_agg[n][k]*wr[k] + s_x[n][k]*wo[k];
        h1[(bl*64 + n)*256 + t] = f2bf(fmaxf(v, 0.f));
    }
}

// ---------------------------------------------------------------------------
// gconv2 aggregation (unchanged — validated)
// ---------------------------------------------------------------------------
__launch_bounds__(256)
__global__ void gconv2_agg_k(int b0, const ushortT* __restrict__ h1, const int* __restrict__ edges,
                             const void* __restrict__ ea,
                             const void* __restrict__ wembW, const void* __restrict__ wembB,
                             ushortT* __restrict__ agg2, const int* __restrict__ flagp)
{
    const int f = *flagp;
    const int bl = blockIdx.x, g = b0 + bl, t = threadIdx.x;
    __shared__ int   s_cnt[64];
    __shared__ int   s_off[65];
    __shared__ int   s_src[512];
    __shared__ float s_w[512];

    if (t < 64) s_cnt[t] = 0;
    __syncthreads();

    const float w0 = get1(wembW,0,f), w1 = get1(wembW,1,f), w2 = get1(wembW,2,f);
    const float wb = get1(wembB,0,f);
    int sl[2], dl[2], slot[2]; float wv[2];
#pragma unroll
    for (int e2 = 0; e2 < 2; ++e2) {
        const int e = g*512 + t + 256*e2;
        const int s = edges[e], d = edges[EDIR + e];
        sl[e2] = clampi(s - g*64, 0, 63); dl[e2] = clampi(d - g*64, 0, 63);
        const float a0 = get1(ea, 2L*e, f), a1 = get1(ea, 2L*e+1, f);
        wv[e2] = fmaxf(a0*w0 + ((a1 < 0.5f) ? w1 : w2) + wb, 0.f);
        slot[e2] = atomicAdd(&s_cnt[dl[e2]], 1);
    }
    __syncthreads();
    if (t == 0) {
        int r = 0;
        for (int i = 0; i < 64; ++i) { s_off[i] = r; r += s_cnt[i]; }
        s_off[64] = r;
    }
    __syncthreads();
#pragma unroll
    for (int e2 = 0; e2 < 2; ++e2) {
        const int p = s_off[dl[e2]] + slot[e2];
        s_src[p] = sl[e2]; s_w[p] = wv[e2];
    }
    __syncthreads();
    for (int n = 0; n < 64; ++n) {
        float acc = 0.f;
        const int i0 = s_off[n], i1 = s_off[n+1];
        for (int i = i0; i < i1; ++i)
            acc += s_w[i] * bf2f(h1[(bl*64 + s_src[i])*256 + t]);
        agg2[(bl*64 + n)*256 + t] = f2bf(acc);
    }
}

// ---------------------------------------------------------------------------
// GraphNorm (unchanged — validated)
// ---------------------------------------------------------------------------
__launch_bounds__(256)
__global__ void gnorm_k(ushortT* __restrict__ h, const void* __restrict__ gw,
                        const void* __restrict__ gb, const void* __restrict__ gms,
                        const int* __restrict__ flagp)
{
    const int f0 = *flagp;
    const int bl = blockIdx.x, t = threadIdx.x;
#pragma unroll
    for (int f2 = 0; f2 < 2; ++f2) {
        const int f = t + 256*f2;
        float acc = 0.f;
        for (int n = 0; n < 64; ++n) acc += bf2f(h[(bl*64+n)*512 + f]);
        const float m2 = get1(gms, f, f0) * (acc * (1.f/64.f));
        float v = 0.f;
        for (int n = 0; n < 64; ++n) { const float d = bf2f(h[(bl*64+n)*512 + f]) - m2; v += d*d; }
        const float rs = rsqrtf(v*(1.f/64.f) + EPSC);
        const float g = get1(gw, f, f0), bb = get1(gb, f, f0);
        for (int n = 0; n < 64; ++n) {
            const int idx = (bl*64+n)*512 + f;
            h[idx] = f2bf(g * (bf2f(h[idx]) - m2) * rs + bb);
        }
    }
}

// ---------------------------------------------------------------------------
// SplitSyndromes sort (unchanged — validated)
// ---------------------------------------------------------------------------
__launch_bounds__(256)
__global__ void sort_k(const int* __restrict__ edges, int* __restrict__ sorted_orig,
                       int* __restrict__ se, int* __restrict__ te)
{
    const int b = blockIdx.x, t = threadIdx.x;
    __shared__ int s_keep[512];
    __shared__ int s_key[512];
    __shared__ int s_ckey[256];
    __shared__ int s_corig[256];
#pragma unroll
    for (int e2 = 0; e2 < 2; ++e2) {
        const int el = t + 256*e2;
        const int e = b*512 + el;
        const int s = edges[e], d = edges[EDIR + e];
        s_keep[el] = (s > d) ? 1 : 0;
        s_key[el]  = ((s - b*64) << 6) | (d - b*64);
    }
    __syncthreads();
#pragma unroll
    for (int e2 = 0; e2 < 2; ++e2) {
        const int el = t + 256*e2;
        if (s_keep[el]) {
            int pos = 0;
            for (int j = 0; j < el; ++j) pos += s_keep[j];
            s_ckey[pos]  = s_key[el];
            s_corig[pos] = b*512 + el;
        }
    }
    __syncthreads();
    const int ki = s_ckey[t];
    int rank = 0;
    for (int j = 0; j < 256; ++j) {
        const int kj = s_ckey[j];
        rank += (kj < ki || (kj == ki && j < t)) ? 1 : 0;
    }
    const int orig = s_corig[t];
    const int p = b*256 + rank;
    sorted_orig[p] = orig;
    se[p] = edges[orig];
    te[p] = edges[EDIR + orig];
}

// ---------------------------------------------------------------------------
// Build F_c + bvec[ge] = F[e] . kb  (unchanged — validated)
// ---------------------------------------------------------------------------
__launch_bounds__(256)
__global__ void fbuild_k(int b0, int maxn, const ushortT* __restrict__ h,
                         const int* __restrict__ sorted_orig,
                         const int* __restrict__ se, const int* __restrict__ te,
                         const void* __restrict__ ea,
                         const void* __restrict__ eW, const void* __restrict__ eB,
                         const float* __restrict__ kb,
                         ushortT* __restrict__ F, float* __restrict__ bvec,
                         const int* __restrict__ flagp)
{
    const int fl = *flagp;
    const int e = blockIdx.x, t = threadIdx.x;
    __shared__ float red[256];
    const int ge = b0*256 + e;
    const int s = clampi(se[ge] - b0*64, 0, maxn);
    const int d = clampi(te[ge] - b0*64, 0, maxn);
    const int orig = clampi(sorted_orig[ge], 0, EDIR-1);
    const float a0 = get1(ea, 2L*orig, fl), a1 = get1(ea, 2L*orig + 1, fl);
    float partial = 0.f;
#pragma unroll
    for (int c = 0; c < 6; ++c) {
        const int col = c*256 + t;
        float v;
        if (c < 2) {
            v = bf2f(h[(long)s*512 + col]);
        } else if (c < 4) {
            const int ff = col - 512;
            v = fmaxf(a0*get1(eW, ff, fl)
                      + ((a1 < 0.5f) ? get1(eW, 512+ff, fl) : get1(eW, 1024+ff, fl))
                      + get1(eB, ff, fl), 0.f);
        } else {
            v = bf2f(h[(long)d*512 + (col - 1024)]);
        }
        F[(long)e*1536 + col] = f2bf(v);
        partial += v * kb[col];
    }
    const float tot = blockReduceSum(partial, red, t);
    if (t == 0) bvec[ge] = tot;
}

// ---------------- row softmax (unchanged — validated) ----------------
__launch_bounds__(256)
__global__ void softmax_k(float* __restrict__ S)
{
    const long row = blockIdx.x;
    const int t = threadIdx.x;
    __shared__ float red[256];
    const float v = S[row*256 + t];
    red[t] = v; __syncthreads();
#pragma unroll
    for (int s = 128; s > 0; s >>= 1) { if (t < s) red[t] = fmaxf(red[t], red[t+s]); __syncthreads(); }
    const float mx = red[0]; __syncthreads();
    const float e = __expf(v - mx);
    red[t] = e; __syncthreads();
#pragma unroll
    for (int s = 128; s > 0; s >>= 1) { if (t < s) red[t] += red[t+s]; __syncthreads(); }
    const float sum = red[0];
    S[row*256 + t] = e / sum;
}

// ---------------- fused LayerNorm + head dot (unchanged — validated) --------
__launch_bounds__(256)
__global__ void ln_head_k(int b0, const ushortT* __restrict__ F, const void* __restrict__ lng,
                          const void* __restrict__ lnb, const void* __restrict__ hW,
                          const void* __restrict__ hB, float* __restrict__ gout,
                          const int* __restrict__ flagp)
{
    const int fl = *flagp;
    const int e = blockIdx.x, t = threadIdx.x;
    __shared__ float red[256];
    float xv[6];
    float s = 0.f;
#pragma unroll
    for (int c = 0; c < 6; ++c) { xv[c] = bf2f(F[(long)e*1536 + c*256 + t]); s += xv[c]; }
    const float tot = blockReduceSum(s, red, t);
    const float mu = tot * (1.f/1536.f);
    float ss = 0.f;
#pragma unroll
    for (int c = 0; c < 6; ++c) { const float d = xv[c] - mu; ss += d*d; }
    const float tot2 = blockReduceSum(ss, red, t);
    const float rs = rsqrtf(tot2 * (1.f/1536.f) + EPSC);
    float p = 0.f;
#pragma unroll
    for (int c = 0; c < 6; ++c) {
        const int col = c*256 + t;
        p += (get1(lng, col, fl) * (xv[c] - mu) * rs + get1(lnb, col, fl)) * get1(hW, col, fl);
    }
    const float tot3 = blockReduceSum(p, red, t);
    if (t == 0) gout[b0*256 + e] = tot3 + get1(hB, 0, fl);
}

// ---------------- final output assembly (unchanged — validated) -------------
__launch_bounds__(128)
__global__ void final_k(const float* __restrict__ gout, const int* __restrict__ se,
                        const int* __restrict__ te, const int* __restrict__ sorted_orig,
                        const void* __restrict__ ea, float* __restrict__ out,
                        const int* __restrict__ flagp)
{
    const int fl = *flagp;
    const int b = blockIdx.x, j = threadIdx.x;
    const int e0 = b*256 + 2*j, e1 = e0 + 1;
    const float p0 = gout[e0], p1 = gout[e1];
    const int idx = (p1 < p0) ? 1 : 0;
    const float val = idx ? p1 : p0;
    const int eo = idx ? e1 : e0;
    const int orig = clampi(sorted_orig[eo], 0, EDIR-1);
    const float cls = get1(ea, 2L*orig + 1, fl);
    out[(b*128 + j)*2 + 0] = (float)se[e0];
    out[(b*128 + j)*2 + 1] = (float)te[e0];
    out[32768 + b*128 + j] = val;
    out[32768 + 16384 + b*128 + j] = cls;
}

// ---------------------------------------------------------------------------
// Launch: phase-W precombination emits MpT/WvoT (transposed, bf16) so the hot
// GEMMs run on the fast k-contiguous bf16 path.
// ---------------------------------------------------------------------------
extern "C" void kernel_launch(void* const* d_in, const int* in_sizes, int n_in,
                              void* d_out, int out_size, void* d_ws, size_t ws_size,
                              hipStream_t stream)
{
    (void)out_size;

    const void* x     = d_in[0];
    const int*  edges = (const int*)d_in[1];
    const void* ea    = d_in[2];

    int ws0 = 3;
    while (ws0 < n_in && in_sizes[ws0] != 3) ++ws0;
    if (ws0 + 27 > n_in) ws0 = 5;

    const void* wembW  = d_in[ws0 + 0];
    const void* wembB  = d_in[ws0 + 1];
    const void* g1Wrel = d_in[ws0 + 2];
    const void* g1brel = d_in[ws0 + 3];
    const void* g1Wroot= d_in[ws0 + 4];
    const void* g2Wrel = d_in[ws0 + 5];
    const void* g2brel = d_in[ws0 + 6];
    const void* g2Wroot= d_in[ws0 + 7];
    const void* gnw    = d_in[ws0 + 8];
    const void* gnb    = d_in[ws0 + 9];
    const void* gnms   = d_in[ws0 + 10];
    const void* eembW  = d_in[ws0 + 11];
    const void* eembB  = d_in[ws0 + 12];
    const void* qkvW   = d_in[ws0 + 13];
    const void* qkvb   = d_in[ws0 + 14];
    const void* inWq   = d_in[ws0 + 15];
    const void* inWk   = d_in[ws0 + 16];
    const void* inWv   = d_in[ws0 + 17];
    const void* inbq   = d_in[ws0 + 18];
    // inbk (ws0+19): row-constant score terms -> drop in softmax
    const void* inbv   = d_in[ws0 + 20];
    const void* outW   = d_in[ws0 + 21];
    const void* outb   = d_in[ws0 + 22];
    const void* lng    = d_in[ws0 + 23];
    const void* lnb    = d_in[ws0 + 24];
    const void* headW  = d_in[ws0 + 25];
    const void* headb  = d_in[ws0 + 26];

    char* ws = (char*)d_ws;
    size_t off = 0;
    auto alloc = [&](size_t bytes) {
        void* p = ws + off;
        off = (off + bytes + 255) & ~(size_t)255;
        return p;
    };
    // ---- fixed region (~11 MB) ----
    int*     dflag  = (int*)    alloc(256);
    float*   gout   = (float*)  alloc(EKEEP*4);
    int*     sorted = (int*)    alloc(EKEEP*4);
    int*     seg    = (int*)    alloc(EKEEP*4);
    int*     teg    = (int*)    alloc(EKEEP*4);
    float*   bvec   = (float*)  alloc(EKEEP*4);
    float*   bqc    = (float*)  alloc(1536*4);
    float*   bvc    = (float*)  alloc(1536*4);
    float*   kb     = (float*)  alloc(1536*4);
    float*   bvo    = (float*)  alloc(1536*4);
    float*   colpart= (float*)  alloc(64L*1536*4);     // colcomb partials
    ushortT* MpT    = (ushortT*)alloc(1536L*1536*2);   // Mp^T, [n][k]
    ushortT* WvoT   = (ushortT*)alloc(1536L*1536*2);   // Wvo^T, [n][k]
    const size_t fixedB = off;

    // union region: phase-W (Wqc|Wkc, Wvc reuses Wqc) vs chunk scratch
    char* uni = ws + off;
    ushortT* Wqc = (ushortT*)uni;
    ushortT* Wkc = (ushortT*)(uni + ((1536L*1536*2 + 255) & ~255L));
    ushortT* Wvc = Wqc;

    const size_t perG = 64L*512*2 + 2L*64*256*2 + 2L*256*1536*2 + 256L*256*4; // 1.97MB
    int G = 128;
    while (G > 1 && fixedB + (size_t)G*perG + 8192 > ws_size) G >>= 1;

    size_t coff = fixedB;
    auto calloc2 = [&](size_t bytes) {
        void* p = ws + coff;
        coff = (coff + bytes + 255) & ~(size_t)255;
        return p;
    };
    ushortT* h_c  = (ushortT*)calloc2((size_t)G*64*512*2);
    ushortT* h1_c = (ushortT*)calloc2((size_t)G*64*256*2);
    ushortT* ag_c = (ushortT*)calloc2((size_t)G*64*256*2);
    ushortT* F_c  = (ushortT*)calloc2((size_t)G*256*1536*2);
    ushortT* T_c  = (ushortT*)calloc2((size_t)G*256*1536*2);
    float*   S_c  = (float*)  calloc2((size_t)G*256*256*4);

    const float scale = 0.02551551815399144f;  // 1/sqrt(1536)
    const dim3 blk(256);

    detect_k<<<1, blk, 0, stream>>>((const unsigned int*)x, dflag);
    sort_k<<<128, blk, 0, stream>>>(edges, sorted, seg, teg);

    // ---- phase W: weight precombination ----
    gemm_k<ushortT,false,false,false,false,false><<<dim3(24,24,1), blk, 0, stream>>>(
        qkvW, C_RT, 0, inWq, C_RT, 0, (const void*)nullptr, C_BF, 0, 0,
        Wqc, dflag, 1536, 4608, 1536, 1536, 0,0,0, 1.f);
    gemm_k<ushortT,false,false,false,false,false><<<dim3(24,24,1), blk, 0, stream>>>(
        qkvW, C_RT, 1536, inWk, C_RT, 0, (const void*)nullptr, C_BF, 0, 0,
        Wkc, dflag, 1536, 4608, 1536, 1536, 0,0,0, 1.f);
    colcomb_part_k<<<dim3(6,64), blk, 0, stream>>>(qkvb, C_RT, 0, inWq, C_RT, colpart, dflag);
    colcomb_red_k<<<6, blk, 0, stream>>>(colpart, inbq, C_RT, bqc, dflag);
    // MpT = scale * Wkc @ Wqc^T   (Mp^T directly — operands swapped)
    gemm_k<ushortT,true,false,false,false,false><<<dim3(24,24,1), blk, 0, stream>>>(
        Wkc, C_BF, 0, Wqc, C_BF, 0, (const void*)nullptr, C_BF, 0, 0,
        MpT, dflag, 1536, 1536, 1536, 1536, 0,0,0, scale);
    // kb = scale * Wkc @ bqc
    rowdot_k<<<1536, blk, 0, stream>>>(Wkc, bqc, kb, scale);
    // Wvc = qkvW[:,3072:4608] @ inWv  (reuses Wqc slot)
    gemm_k<ushortT,false,false,false,false,false><<<dim3(24,24,1), blk, 0, stream>>>(
        qkvW, C_RT, 3072, inWv, C_RT, 0, (const void*)nullptr, C_BF, 0, 0,
        Wvc, dflag, 1536, 4608, 1536, 1536, 0,0,0, 1.f);
    colcomb_part_k<<<dim3(6,64), blk, 0, stream>>>(qkvb, C_RT, 3072, inWv, C_RT, colpart, dflag);
    colcomb_red_k<<<6, blk, 0, stream>>>(colpart, inbv, C_RT, bvc, dflag);
    // WvoT = (Wvc @ outW)^T  via transposed store
    gemm_k<ushortT,false,false,false,false,true><<<dim3(24,24,1), blk, 0, stream>>>(
        Wvc, C_BF, 0, outW, C_RT, 0, (const void*)nullptr, C_BF, 0, 0,
        WvoT, dflag, 1536, 1536, 1536, 1536, 0,0,0, 1.f);
    colcomb_part_k<<<dim3(6,64), blk, 0, stream>>>(bvc, C_F32, 0, outW, C_RT, colpart, dflag);
    colcomb_red_k<<<6, blk, 0, stream>>>(colpart, outb, C_RT, bvo, dflag);

    // ---- per-chunk pipeline ----
    const int nchunk = 128 / G;
    const int EC = G * 256;
    for (int c = 0; c < nchunk; ++c) {
        const int b0 = c * G;
        gconv1_k<<<G, blk, 0, stream>>>(b0, x, edges, ea, wembW, wembB,
                                        g1Wrel, g1brel, g1Wroot, h1_c, dflag);
        gconv2_agg_k<<<G, blk, 0, stream>>>(b0, h1_c, edges, ea, wembW, wembB, ag_c, dflag);
        gemm_k<ushortT,false,true,false,false,false><<<dim3(8,G,1), blk, 0, stream>>>(
            ag_c, C_BF, 0, g2Wrel, C_RT, 0, g2brel, C_RT, 0, 0, h_c, dflag,
            256, 256, 512, 512, 0,0,0, 1.f);
        gemm_k<ushortT,false,false,true,true,false><<<dim3(8,G,1), blk, 0, stream>>>(
            h1_c, C_BF, 0, g2Wroot, C_RT, 0, (const void*)nullptr, C_BF, 0, 0, h_c, dflag,
            256, 256, 512, 512, 0,0,0, 1.f);
        gnorm_k<<<G, blk, 0, stream>>>(h_c, gnw, gnb, gnms, dflag);
        fbuild_k<<<EC, blk, 0, stream>>>(b0, G*64-1, h_c, sorted, seg, teg, ea,
                                         eembW, eembB, kb, F_c, bvec, dflag);
        // T = F @ MpT^T   (fast bf16 path)
        bgemm_k<ushortT,false,false><<<dim3(12, EC/128, 1), blk, 0, stream>>>(
            F_c, MpT, nullptr, T_c, 1536, 1536, 1536, 1536, 0,0,0, 0,0, 1.f);
        // S_b = T_b @ F_b^T + bvec
        bgemm_k<float,true,false><<<dim3(2, 2, G), blk, 0, stream>>>(
            T_c, F_c, bvec + (long)b0*256, S_c, 1536, 1536, 1536, 256,
            256L*1536, 256L*1536, 65536L, 0, 256, 1.f);
        softmax_k<<<EC, blk, 0, stream>>>(S_c);
        // R_b = P_b @ F_b  -> T_c (generic path: A is f32)
        gemm_k<ushortT,false,false,false,false,false><<<dim3(24,4,G), blk, 0, stream>>>(
            S_c, C_F32, 0, F_c, C_BF, 0, (const void*)nullptr, C_BF, 0, 0, T_c, dflag,
            256, 256, 1536, 1536, 65536L, 256L*1536, 256L*1536, 1.f);
        // F += R @ WvoT^T + bvo   (fast bf16 path, residual)
        bgemm_k<ushortT,true,true><<<dim3(12, EC/128, 1), blk, 0, stream>>>(
            T_c, WvoT, bvo, F_c, 1536, 1536, 1536, 1536, 0,0,0, 0,0, 1.f);
        ln_head_k<<<EC, blk, 0, stream>>>(b0, F_c, lng, lnb, headW, headb, gout, dflag);
    }

    final_k<<<128, dim3(128), 0, stream>>>(gout, seg, teg, sorted, ea, (float*)d_out, dflag);
}